// Round 8
// baseline (1194.171 us; speedup 1.0000x reference)
//
#include <hip/hip_runtime.h>
#include <hip/hip_bf16.h>
#include <math.h>

#define NN 50000
#define NE 800000
#define NG 64
#define NC 100
#define EPSV 1e-5f
#define PBN 256   // BN partial-sum base slots (deterministic, no atomics)
#define SCB 196   // scan blocks (196*256 >= NN)
#define SPL 8     // pool splits per graph

typedef unsigned int   u32;
typedef unsigned short u16;
typedef __attribute__((ext_vector_type(8))) short bf16x8;
typedef __attribute__((ext_vector_type(4))) float f32x4;

__device__ __forceinline__ float gelu_f(float x){
  return 0.5f*x*(1.0f + erff(x*0.70710678118654752f));
}
__device__ __forceinline__ float bf2f(u16 u){
  return __uint_as_float(((u32)u)<<16);
}
__device__ __forceinline__ float2 bf2f2(u32 u){
  float2 r;
  r.x = __uint_as_float(u<<16);
  r.y = __uint_as_float(u & 0xffff0000u);
  return r;
}
__device__ __forceinline__ u16 f2bf(float f){
  __hip_bfloat16 h = __float2bfloat16(f);
  return *(u16*)&h;
}
__device__ __forceinline__ u32 pack_bf2(float a, float b){
  return (u32)f2bf(a) | ((u32)f2bf(b)<<16);
}

// ---------------- CSR construction ----------------
__global__ void k_deg_init(int* deg){
  int i = blockIdx.x*256 + threadIdx.x;
  if (i < NN) deg[i] = 1;           // self loop
}
__global__ void k_deg_hist(const int* ei, int* deg){
  int e = blockIdx.x*256 + threadIdx.x;
  if (e < NE) atomicAdd(&deg[ei[NE + e]], 1);   // dst row
}
__global__ void k_dis(const int* deg, float* dis){
  int i = blockIdx.x*256 + threadIdx.x;
  if (i < NN) dis[i] = rsqrtf((float)deg[i]);
}
// parallel exclusive scan of (deg-1)
__global__ void k_scanA(const int* deg, int* bsum){
  __shared__ int red[256];
  int b = blockIdx.x, t = threadIdx.x;
  int i = b*256 + t;
  red[t] = (i < NN) ? deg[i]-1 : 0;
  __syncthreads();
  for (int st = 128; st; st >>= 1){
    if (t < st) red[t] += red[t+st];
    __syncthreads();
  }
  if (t == 0) bsum[b] = red[0];
}
__global__ void k_scanB(const int* bsum, int* boff){
  __shared__ int sh[256];
  int t = threadIdx.x;
  sh[t] = (t < SCB) ? bsum[t] : 0;
  __syncthreads();
  for (int d = 1; d < 256; d <<= 1){
    int v = (t >= d) ? sh[t-d] : 0;
    __syncthreads();
    sh[t] += v;
    __syncthreads();
  }
  if (t == 0) boff[0] = 0;
  if (t < SCB) boff[t+1] = sh[t];
}
__global__ void k_scanC(const int* deg, const int* boff, int* off, int* cur){
  __shared__ int sh[256];
  int b = blockIdx.x, t = threadIdx.x;
  int i = b*256 + t;
  int v = (i < NN) ? deg[i]-1 : 0;
  sh[t] = v;
  __syncthreads();
  for (int d = 1; d < 256; d <<= 1){
    int u = (t >= d) ? sh[t-d] : 0;
    __syncthreads();
    sh[t] += u;
    __syncthreads();
  }
  if (i < NN){
    int excl = boff[b] + sh[t] - v;
    off[i] = excl; cur[i] = excl;
    if (i == NN-1) off[NN] = boff[b] + sh[t];
  }
}
__global__ void k_scatter(const int* ei, int* cur, int* col){
  int e = blockIdx.x*256 + threadIdx.x;
  if (e < NE){
    int s = ei[e], d = ei[NE + e];
    int p = atomicAdd(&cur[d], 1);
    col[p] = s;
  }
}

// ---------------- GCN1: aggregate in 3-dim input space ----------------
__global__ void k_agg3(const float* x, const int* off, const int* col,
                       const float* dis, float* aggx){
  int i = blockIdx.x*256 + threadIdx.x;
  if (i >= NN) return;
  float di = dis[i];
  float w0 = di*di;
  float a0 = w0*x[i*3], a1 = w0*x[i*3+1], a2 = w0*x[i*3+2];
  int lo = off[i], hi = off[i+1];
  for (int e = lo; e < hi; ++e){
    int s = col[e];
    float w = dis[s]*di;
    a0 += w*x[s*3]; a1 += w*x[s*3+1]; a2 += w*x[s*3+2];
  }
  aggx[i*3] = a0; aggx[i*3+1] = a1; aggx[i*3+2] = a2;
}

// ---------------- input matmul (K=3) ----------------
__global__ void k_mm_in(const float* aggx, const float* w, const float* bias, u32* outp){
  int gid = blockIdx.x*256 + threadIdx.x;
  if (gid >= NN*64) return;
  int i = gid >> 6, j2 = (gid & 63)*2;
  float a = aggx[i*3]*w[j2]   + aggx[i*3+1]*w[128+j2]   + aggx[i*3+2]*w[256+j2]   + bias[j2];
  float b = aggx[i*3]*w[j2+1] + aggx[i*3+1]*w[128+j2+1] + aggx[i*3+2]*w[256+j2+1] + bias[j2+1];
  outp[gid] = pack_bf2(a, b);
}

// ---------------- B pre-conversion to bf16 fragment-major ----------------
__global__ void k_prepB(const float* B, int ldB, int K, int ncc, u16* Bf){
  int gid = blockIdx.x*256 + threadIdx.x;
  int tot = ncc*K*128;
  if (gid >= tot) return;
  int cc = gid / (K*128);
  int rem = gid - cc*(K*128);
  int k = rem >> 7, n = rem & 127;
  int c128 = k >> 7, kk = k & 127;
  int nt = n >> 4, i = n & 15;
  int ks = kk >> 5, jg = (kk >> 3) & 3, e = kk & 7;
  size_t addr = (size_t)cc*K*128 +
                ((((size_t)(c128*8 + nt)*4 + ks)*4 + jg)*16 + i)*8 + e;
  Bf[addr] = f2bf(B[(size_t)k*ldB + cc*128 + n]);
}
__global__ void k_prepBG(const float* w_gat, u16* Bf){
  int gid = blockIdx.x*256 + threadIdx.x;
  if (gid >= 640*128) return;
  int k = gid >> 7, n = gid & 127;
  int h = k >> 7, kk = k & 127;
  int nt = n >> 4, i = n & 15;
  int ks = kk >> 5, jg = (kk >> 3) & 3, e = kk & 7;
  size_t addr = ((((size_t)(h*8 + nt)*4 + ks)*4 + jg)*16 + i)*8 + e;
  Bf[addr] = f2bf(0.2f * w_gat[(size_t)kk*640 + h*128 + n]);
}

// ---------------- MFMA matmul (coalesced C store via LDS) ----------------
__global__ __launch_bounds__(256) void k_mm_mfma(const u16* A, int lda, int M, int K,
                        const u16* Bf, u16* C, int ldC, const float* bias){
  __shared__ u16 ct[64*132];
  int tid = threadIdx.x;
  int w = tid >> 6, l = tid & 63;
  int jg = l >> 4, ii = l & 15;
  int m0 = blockIdx.x*64 + w*16;
  int cc = blockIdx.y;
  int arow = m0 + ii; if (arow >= M) arow = M-1;
  const u16* Bfc = Bf + (size_t)cc*K*128;
  f32x4 acc[8] = {};
  for (int c128 = 0; c128 < (K >> 7); ++c128){
    const u16* Ar = A + (size_t)arow*lda + c128*128;
    bf16x8 af[4];
    #pragma unroll
    for (int ks = 0; ks < 4; ++ks)
      af[ks] = *(const bf16x8*)(Ar + ks*32 + jg*8);
    #pragma unroll
    for (int nt = 0; nt < 8; ++nt){
      f32x4 a4 = acc[nt];
      #pragma unroll
      for (int ks = 0; ks < 4; ++ks){
        bf16x8 bfr = *(const bf16x8*)(Bfc +
            ((((size_t)(c128*8 + nt)*4 + ks)*4 + jg)*16 + ii)*8);
        a4 = __builtin_amdgcn_mfma_f32_16x16x32_bf16(af[ks], bfr, a4, 0, 0, 0);
      }
      acc[nt] = a4;
    }
  }
  int cOut = cc*128;
  int lrow0 = w*16 + jg*4;
  #pragma unroll
  for (int nt = 0; nt < 8; ++nt){
    float bv = bias[cOut + nt*16 + ii];
    #pragma unroll
    for (int r = 0; r < 4; ++r)
      ct[(lrow0 + r)*132 + nt*16 + ii] = f2bf(acc[nt][r] + bv);
  }
  __syncthreads();
  int lr0 = tid >> 6;
  int lc = tid & 63;
  #pragma unroll
  for (int rr = 0; rr < 16; ++rr){
    int lrow = rr*4 + lr0;
    int grow = blockIdx.x*64 + lrow;
    if (grow < M)
      *(u32*)(C + (size_t)grow*ldC + cOut + lc*2) = *(const u32*)(ct + lrow*132 + lc*2);
  }
}

// ---------------- GCN aggregate in 128-dim ----------------
__global__ void k_gcn_agg64(const u16* xw, const int* off, const int* col,
                            const float* dis, u16* out){
  int i = blockIdx.x, t = threadIdx.x;   // 64 threads
  float di = dis[i];
  float2 sv = bf2f2(((const u32*)(xw + (size_t)i*128))[t]);
  float w0 = di*di;
  float ax = w0*sv.x, ay = w0*sv.y;
  int lo = off[i], hi = off[i+1];
  int e = lo;
  for (; e + 4 <= hi; e += 4){
    int s0 = col[e], s1 = col[e+1], s2 = col[e+2], s3 = col[e+3];
    float wA = dis[s0]*di, wB = dis[s1]*di, wC = dis[s2]*di, wD = dis[s3]*di;
    float2 r0 = bf2f2(((const u32*)(xw + (size_t)s0*128))[t]);
    float2 r1 = bf2f2(((const u32*)(xw + (size_t)s1*128))[t]);
    float2 r2 = bf2f2(((const u32*)(xw + (size_t)s2*128))[t]);
    float2 r3 = bf2f2(((const u32*)(xw + (size_t)s3*128))[t]);
    ax += wA*r0.x; ay += wA*r0.y;
    ax += wB*r1.x; ay += wB*r1.y;
    ax += wC*r2.x; ay += wC*r2.y;
    ax += wD*r3.x; ay += wD*r3.y;
  }
  for (; e < hi; ++e){
    int s = col[e];
    float w = dis[s]*di;
    float2 rv = bf2f2(((const u32*)(xw + (size_t)s*128))[t]);
    ax += w*rv.x; ay += w*rv.y;
  }
  ((u32*)(out + (size_t)i*128))[t] = pack_bf2(ax, ay);
}

// ---------------- BatchNorm (vectorized deterministic partial sums) ----------------
// 256 threads = 32 f-threads (ushort4) x 8 row lanes; slot = p*8+rl
__global__ void k_bn_part(const u16* x, int stride, int W, float* part){
  int t = threadIdx.x;
  int ft = t & 31, rl = t >> 5;
  int f0 = blockIdx.x*128 + ft*4;
  int p = blockIdx.y;
  int slot = p*8 + rl;
  float s0=0.f,s1=0.f,s2=0.f,s3=0.f, q0=0.f,q1=0.f,q2=0.f,q3=0.f;
  for (int r = p + PBN*rl; r < NN; r += PBN*8){
    ushort4 u = *(const ushort4*)(x + (size_t)r*stride + f0);
    float v0 = bf2f(u.x), v1 = bf2f(u.y), v2 = bf2f(u.z), v3 = bf2f(u.w);
    s0 += v0; s1 += v1; s2 += v2; s3 += v3;
    q0 += v0*v0; q1 += v1*v1; q2 += v2*v2; q3 += v3*v3;
  }
  float* pb = part + (size_t)slot*2*W;
  pb[f0] = s0; pb[f0+1] = s1; pb[f0+2] = s2; pb[f0+3] = s3;
  pb[W+f0] = q0; pb[W+f0+1] = q1; pb[W+f0+2] = q2; pb[W+f0+3] = q3;
}
__global__ void k_bn_fin(const float* part, const float* g, const float* be,
                         float* ss, int W, float invn){
  int f = blockIdx.x*256 + threadIdx.x;
  if (f >= W) return;
  float s = 0.f, q = 0.f;
  for (int p = 0; p < PBN*8; ++p){
    s += part[(size_t)p*2*W + f];
    q += part[(size_t)p*2*W + W + f];
  }
  float mean = s*invn;
  float var  = q*invn - mean*mean;
  float sc = g[f]*rsqrtf(var + EPSV);
  ss[f] = sc;
  ss[W+f] = be[f] - mean*sc;
}
template<bool RES>
__global__ void k_bn_apply(const u32* x, const float* ss, const u32* res, u32* out){
  const int n = NN*64;
  for (int idx = blockIdx.x*256 + threadIdx.x; idx < n; idx += gridDim.x*256){
    int f2 = (idx & 63)*2;
    float2 v = bf2f2(x[idx]);
    v.x = gelu_f(v.x*ss[f2]   + ss[128+f2]);
    v.y = gelu_f(v.y*ss[f2+1] + ss[128+f2+1]);
    if (RES){ float2 r = bf2f2(res[idx]); v.x += r.x; v.y += r.y; }
    out[idx] = pack_bf2(v.x, v.y);
  }
}

// ---------------- GAT ----------------
__global__ void k_wv(const float* w_gat, const float* att_s, const float* att_d,
                     float* wvs, float* wvd){
  int h = blockIdx.x, c = threadIdx.x;   // 5 blocks x 128
  float ss = 0.f, sd = 0.f;
  const float* wr = w_gat + (size_t)c*640 + h*128;
  const float* as = att_s + h*128;
  const float* ad = att_d + h*128;
  for (int k = 0; k < 128; ++k){
    float wv = wr[k];
    ss += wv*as[k]; sd += wv*ad[k];
  }
  wvs[h*128+c] = ss; wvd[h*128+c] = sd;
}

__global__ void k_score10(const u16* h2, const float* wvs, const float* wvd,
                          float* asrc, float* adst){
  int i = blockIdx.x, t = threadIdx.x;   // 64
  float2 v = bf2f2(((const u32*)(h2 + (size_t)i*128))[t]);
  int f2 = 2*t;
  #pragma unroll
  for (int h = 0; h < 5; ++h){
    float vs = v.x*wvs[h*128+f2] + v.y*wvs[h*128+f2+1];
    float vd = v.x*wvd[h*128+f2] + v.y*wvd[h*128+f2+1];
    #pragma unroll
    for (int d = 32; d; d >>= 1){ vs += __shfl_xor(vs, d); vd += __shfl_xor(vd, d); }
    if (t == 0){ asrc[i*5+h] = vs; adst[i*5+h] = vd; }
  }
}

// single pass, max-free softmax prep; numerators bf16-packed [NE][8]
__global__ void k_prep5(const float* asrc, const float* adst,
                        const int* off, const int* col,
                        u16* sv, float* aself5, float* invb5){
  int i = blockIdx.x, t = threadIdx.x;   // 64
  int lo = off[i], hi = off[i+1];
  float ad[5], dn[5];
  #pragma unroll
  for (int h = 0; h < 5; ++h){ ad[h] = adst[i*5+h]; dn[h] = 0.f; }
  for (int e = lo + t; e < hi; e += 64){
    int s = col[e];
    u16 nb[5];
    #pragma unroll
    for (int h = 0; h < 5; ++h){
      float v = asrc[s*5+h] + ad[h];
      v = (v > 0.f) ? v : 0.2f*v;
      float ex = expf(v);
      u16 qq = f2bf(ex);
      nb[h] = qq;
      dn[h] += bf2f(qq);
    }
    uint4 pk;
    pk.x = (u32)nb[0] | ((u32)nb[1] << 16);
    pk.y = (u32)nb[2] | ((u32)nb[3] << 16);
    pk.z = (u32)nb[4];
    pk.w = 0;
    *(uint4*)(sv + (size_t)e*8) = pk;
  }
  #pragma unroll
  for (int h = 0; h < 5; ++h)
    #pragma unroll
    for (int d = 32; d; d >>= 1) dn[h] += __shfl_xor(dn[h], d);
  if (t == 0){
    #pragma unroll
    for (int h = 0; h < 5; ++h){
      float es = asrc[i*5+h] + ad[h];
      es = (es > 0.f) ? es : 0.2f*es;
      float esf = expf(es);
      aself5[i*5+h] = esf;
      invb5[i*5+h] = 1.f/fmaxf(dn[h] + esf, 1e-16f);
    }
  }
}

// one gather pass, 5 alpha-weighted accumulators; agg5 [NN,640] bf16
__global__ void k_gather5(const u16* h2, const int* off, const int* col,
                          const u16* sv, const float* aself5, const float* invb5,
                          u16* agg5){
  int i = blockIdx.x, t = threadIdx.x;   // 64
  float2 svv = bf2f2(((const u32*)(h2 + (size_t)i*128))[t]);
  float ax[5], ay[5];
  #pragma unroll
  for (int h = 0; h < 5; ++h){
    float a = aself5[i*5+h];
    ax[h] = a*svv.x; ay[h] = a*svv.y;
  }
  int lo = off[i], hi = off[i+1];
  int e = lo;
  for (; e + 2 <= hi; e += 2){
    int s0 = col[e], s1 = col[e+1];
    uint4 p0 = *(const uint4*)(sv + (size_t)e*8);
    uint4 p1 = *(const uint4*)(sv + (size_t)(e+1)*8);
    float2 r0 = bf2f2(((const u32*)(h2 + (size_t)s0*128))[t]);
    float2 r1 = bf2f2(((const u32*)(h2 + (size_t)s1*128))[t]);
    float a00 = bf2f((u16)(p0.x & 0xffff)), a01 = bf2f((u16)(p0.x >> 16));
    float a02 = bf2f((u16)(p0.y & 0xffff)), a03 = bf2f((u16)(p0.y >> 16));
    float a04 = bf2f((u16)(p0.z & 0xffff));
    float a10 = bf2f((u16)(p1.x & 0xffff)), a11 = bf2f((u16)(p1.x >> 16));
    float a12 = bf2f((u16)(p1.y & 0xffff)), a13 = bf2f((u16)(p1.y >> 16));
    float a14 = bf2f((u16)(p1.z & 0xffff));
    ax[0] += a00*r0.x + a10*r1.x; ay[0] += a00*r0.y + a10*r1.y;
    ax[1] += a01*r0.x + a11*r1.x; ay[1] += a01*r0.y + a11*r1.y;
    ax[2] += a02*r0.x + a12*r1.x; ay[2] += a02*r0.y + a12*r1.y;
    ax[3] += a03*r0.x + a13*r1.x; ay[3] += a03*r0.y + a13*r1.y;
    ax[4] += a04*r0.x + a14*r1.x; ay[4] += a04*r0.y + a14*r1.y;
  }
  for (; e < hi; ++e){
    int s = col[e];
    uint4 pk = *(const uint4*)(sv + (size_t)e*8);
    float2 rv = bf2f2(((const u32*)(h2 + (size_t)s*128))[t]);
    float a0 = bf2f((u16)(pk.x & 0xffff)), a1 = bf2f((u16)(pk.x >> 16));
    float a2 = bf2f((u16)(pk.y & 0xffff)), a3 = bf2f((u16)(pk.y >> 16));
    float a4 = bf2f((u16)(pk.z & 0xffff));
    ax[0] += a0*rv.x; ay[0] += a0*rv.y;
    ax[1] += a1*rv.x; ay[1] += a1*rv.y;
    ax[2] += a2*rv.x; ay[2] += a2*rv.y;
    ax[3] += a3*rv.x; ay[3] += a3*rv.y;
    ax[4] += a4*rv.x; ay[4] += a4*rv.y;
  }
  #pragma unroll
  for (int h = 0; h < 5; ++h){
    float iv = invb5[i*5+h];
    ((u32*)(agg5 + (size_t)i*640 + h*128))[t] = pack_bf2(ax[h]*iv, ay[h]*iv);
  }
}

// ---------------- fused graph-LN stats + mean pool (single pass over A512) -------
__global__ void k_gstart(const int* batch, int* gs){
  int g = threadIdx.x;
  if (g > NG) return;
  int lo = 0, hi = NN;
  while (lo < hi){ int mid = (lo+hi) >> 1; if (batch[mid] < g) lo = mid+1; else hi = mid; }
  gs[g] = lo;
}
// grid (NG, SPL) x 512 threads: 128 f-threads (ushort4) x 4 row lanes
__global__ void k_poolstat(const u16* a512, const float* ss, const int* gs,
                           float* poolpart, float* sqpart){
  __shared__ float4 red4[512];
  __shared__ float redq[512];
  int g = blockIdx.x, sp = blockIdx.y, t = threadIdx.x;
  int ft = t & 127, rl = t >> 7;
  int f0 = ft*4;
  int lo = gs[g], hi = gs[g+1];
  float sc0 = ss[f0],     sc1 = ss[f0+1],     sc2 = ss[f0+2],     sc3 = ss[f0+3];
  float sh0 = ss[512+f0], sh1 = ss[512+f0+1], sh2 = ss[512+f0+2], sh3 = ss[512+f0+3];
  float4 s4 = {0.f,0.f,0.f,0.f};
  float q = 0.f;
  for (int r = lo + sp*4 + rl; r < hi; r += SPL*4){
    ushort4 u = *(const ushort4*)(a512 + (size_t)r*512 + f0);
    float v0 = gelu_f(bf2f(u.x)*sc0 + sh0);
    float v1 = gelu_f(bf2f(u.y)*sc1 + sh1);
    float v2 = gelu_f(bf2f(u.z)*sc2 + sh2);
    float v3 = gelu_f(bf2f(u.w)*sc3 + sh3);
    s4.x += v0; s4.y += v1; s4.z += v2; s4.w += v3;
    q += v0*v0 + v1*v1 + v2*v2 + v3*v3;
  }
  red4[t] = s4; redq[t] = q;
  __syncthreads();
  for (int st = 256; st; st >>= 1){
    if (t < st) redq[t] += redq[t+st];
    __syncthreads();
  }
  if (t == 0) sqpart[g*SPL + sp] = redq[0];
  if (rl == 0){
    float4 a = red4[t], b = red4[t+128], c = red4[t+256], d = red4[t+384];
    float4 o;
    o.x = a.x+b.x+c.x+d.x; o.y = a.y+b.y+c.y+d.y;
    o.z = a.z+b.z+c.z+d.z; o.w = a.w+b.w+c.w+d.w;
    ((float4*)poolpart)[((size_t)(g*SPL + sp))*128 + ft] = o;
  }
}
__global__ void k_poolred(const float* poolpart, const float* sqpart, float* scal){
  __shared__ float rs_[1024], rq_[1024];
  int t = threadIdx.x;
  float s = 0.f, q = 0.f;
  const int tot = NG*SPL*512;
  for (int i = t; i < tot; i += 1024) s += poolpart[i];
  for (int i = t; i < NG*SPL; i += 1024) q += sqpart[i];
  rs_[t] = s; rq_[t] = q;
  __syncthreads();
  for (int st = 512; st; st >>= 1){
    if (t < st){ rs_[t] += rs_[t+st]; rq_[t] += rq_[t+st]; }
    __syncthreads();
  }
  if (t == 0){
    float invn = 1.f/((float)NN*512.f);
    float mu  = rs_[0]*invn;
    float var = rq_[0]*invn - mu*mu;
    scal[2] = mu;
    scal[3] = rsqrtf(var + EPSV);
  }
}
__global__ void k_poolapply(const float* poolpart, const int* gs, const float* scal,
                            const float* gam, const float* bet, float* pooled){
  int g = blockIdx.x, f = threadIdx.x;   // 512
  float s = 0.f;
  #pragma unroll
  for (int sp = 0; sp < SPL; ++sp)
    s += poolpart[((size_t)(g*SPL + sp))*512 + f];
  float cnt = (float)max(gs[g+1] - gs[g], 1);
  pooled[g*512 + f] = (s/cnt - scal[2])*scal[3]*gam[f] + bet[f];
}

// ---------------- projection head + classifier (fp32, tiny) ----------------
__global__ void k_head_mm1(const float* pooled, const float* w, const float* b, float* q){
  int g = blockIdx.x, j = threadIdx.x;   // 128
  float s = b[j];
  const float* pr = pooled + g*512;
  for (int k = 0; k < 512; ++k) s += pr[k]*w[k*128+j];
  q[g*128+j] = s;
}
__global__ void k_head_bn(const float* qin, const float* g_, const float* be_, float* qout){
  int f = threadIdx.x;   // 128, single block
  float s = 0.f, sq = 0.f;
  for (int r = 0; r < NG; ++r){ float v = qin[r*128+f]; s += v; sq += v*v; }
  float mu = s*(1.f/NG), var = sq*(1.f/NG) - mu*mu;
  float sc = g_[f]*rsqrtf(var + EPSV);
  float sh = be_[f] - mu*sc;
  for (int r = 0; r < NG; ++r) qout[r*128+f] = gelu_f(qin[r*128+f]*sc + sh);
}
// head2 (mm + res + LN + L2-normalize) fused with classifier (log-softmax)
__global__ void k_head2c(const float* q2, const float* w, const float* b,
                         const float* gam, const float* bet,
                         const float* wc, const float* bc, float* out){
  int g = blockIdx.x, j = threadIdx.x;   // 128
  __shared__ float row[128], red[128], shv[3];
  row[j] = q2[g*128+j];
  __syncthreads();
  float s = b[j] + row[j];
  for (int k = 0; k < 128; ++k) s += row[k]*w[k*128+j];
  red[j] = s; __syncthreads();
  for (int st = 64; st; st >>= 1){ if (j < st) red[j] += red[j+st]; __syncthreads(); }
  if (j == 0) shv[0] = red[0]*(1.f/128.f);
  __syncthreads();
  float d = s - shv[0];
  red[j] = d*d; __syncthreads();
  for (int st = 64; st; st >>= 1){ if (j < st) red[j] += red[j+st]; __syncthreads(); }
  if (j == 0) shv[1] = rsqrtf(red[0]*(1.f/128.f) + EPSV);
  __syncthreads();
  float v = d*shv[1]*gam[j] + bet[j];
  red[j] = v*v; __syncthreads();
  for (int st = 64; st; st >>= 1){ if (j < st) red[j] += red[j+st]; __syncthreads(); }
  if (j == 0) shv[2] = 1.f/fmaxf(sqrtf(red[0]), 1e-12f);
  __syncthreads();
  float o = v*shv[2];
  out[g*128+j] = o;
  __syncthreads();
  row[j] = o;        // x1 row for classifier
  __syncthreads();
  float cs = -1e30f;
  if (j < NC){
    cs = bc[j];
    for (int k = 0; k < 128; ++k) cs += row[k]*wc[k*NC+j];
  }
  red[j] = cs; __syncthreads();
  for (int st = 64; st; st >>= 1){ if (j < st) red[j] = fmaxf(red[j], red[j+st]); __syncthreads(); }
  if (j == 0) shv[0] = red[0];
  __syncthreads();
  float e = (j < NC) ? expf(cs - shv[0]) : 0.f;
  red[j] = e; __syncthreads();
  for (int st = 64; st; st >>= 1){ if (j < st) red[j] += red[j+st]; __syncthreads(); }
  if (j == 0) shv[1] = logf(red[0]);
  __syncthreads();
  if (j < NC) out[NG*128 + g*NC+j] = cs - shv[0] - shv[1];
}

extern "C" void kernel_launch(void* const* d_in, const int* in_sizes, int n_in,
                              void* d_out, int out_size, void* d_ws, size_t ws_size,
                              hipStream_t stream){
  const float* x      = (const float*)d_in[0];
  const int*   ei     = (const int*)d_in[1];
  const int*   batch  = (const int*)d_in[2];
  const float* w_in   = (const float*)d_in[3];
  const float* b_in   = (const float*)d_in[4];
  const float* g_in   = (const float*)d_in[5];
  const float* be_in  = (const float*)d_in[6];
  const float* w_h    = (const float*)d_in[7];
  const float* b_h    = (const float*)d_in[8];
  const float* g_h    = (const float*)d_in[9];
  const float* be_h   = (const float*)d_in[10];
  const float* w_gat  = (const float*)d_in[11];
  const float* att_s  = (const float*)d_in[12];
  const float* att_d  = (const float*)d_in[13];
  const float* b_gat  = (const float*)d_in[14];
  const float* w_out  = (const float*)d_in[15];
  const float* b_out  = (const float*)d_in[16];
  const float* g_out  = (const float*)d_in[17];
  const float* be_out = (const float*)d_in[18];
  const float* g_ln   = (const float*)d_in[19];
  const float* be_ln  = (const float*)d_in[20];
  const float* w_p1   = (const float*)d_in[21];
  const float* b_p1   = (const float*)d_in[22];
  const float* g_pbn  = (const float*)d_in[23];
  const float* be_pbn = (const float*)d_in[24];
  const float* w_p2   = (const float*)d_in[25];
  const float* b_p2   = (const float*)d_in[26];
  const float* g_pln  = (const float*)d_in[27];
  const float* be_pln = (const float*)d_in[28];
  const float* w_c    = (const float*)d_in[29];
  const float* b_c    = (const float*)d_in[30];
  float* out = (float*)d_out;

  char* ws = (char*)d_ws;
  size_t o = 0;
  auto carve = [&](size_t bytes) -> char* {
    char* p = ws + o;
    o += (bytes + 255) & ~(size_t)255;
    return p;
  };
  int*   deg    = (int*)  carve((size_t)NN*4);
  int*   off    = (int*)  carve((size_t)(NN+1)*4);
  int*   cur    = (int*)  carve((size_t)NN*4);
  int*   col    = (int*)  carve((size_t)NE*4);
  float* dis    = (float*)carve((size_t)NN*4);
  int*   bsum   = (int*)  carve((size_t)SCB*4);
  int*   boff   = (int*)  carve((size_t)(SCB+1)*4);
  float* aggx3  = (float*)carve((size_t)NN*3*4);
  u16*   F0     = (u16*)  carve((size_t)NN*128*2);   // 12.8 MB
  u16*   F1     = (u16*)  carve((size_t)NN*128*2);
  u16*   F2     = (u16*)  carve((size_t)NN*128*2);   // aliased as sv during GAT
  u16*   AGG5   = (u16*)  carve((size_t)NN*640*2);   // 64 MB; later aliased as A512
  float* asrc   = (float*)carve((size_t)NN*5*4);
  float* adst   = (float*)carve((size_t)NN*5*4);
  float* aself5 = (float*)carve((size_t)NN*5*4);
  float* invb5  = (float*)carve((size_t)NN*5*4);
  float* wvs    = (float*)carve(640*4);
  float* wvd    = (float*)carve(640*4);
  u16*   BfH    = (u16*)  carve((size_t)128*128*2);
  u16*   BfG    = (u16*)  carve((size_t)640*128*2);
  u16*   BfO    = (u16*)  carve((size_t)128*512*2);
  float* part   = (float*)carve((size_t)PBN*8*1024*4); // 8 MB (slots x 2W max)
  float* poolpart = (float*)carve((size_t)NG*SPL*512*4); // 1 MB
  float* sqpart = (float*)carve((size_t)NG*SPL*4);
  float* ssbuf  = (float*)carve(1024*4);
  float* scal   = (float*)carve(64);
  int*   gst    = (int*)  carve(65*4);
  float* pooled = (float*)carve((size_t)NG*512*4);
  float* q      = (float*)carve((size_t)NG*128*4);
  float* q2     = (float*)carve((size_t)NG*128*4);
  if (o > ws_size) return;   // ~124 MB total

  u16* A512 = AGG5;        // [NN,512] bf16 reuses AGG5 (dead by then)
  u16* sv   = F2;          // [NE][8] bf16 numerators

  // ---- CSR build ----
  k_deg_init<<<196,256,0,stream>>>(deg);
  k_deg_hist<<<3125,256,0,stream>>>(ei, deg);
  k_dis<<<196,256,0,stream>>>(deg, dis);
  k_scanA<<<SCB,256,0,stream>>>(deg, bsum);
  k_scanB<<<1,256,0,stream>>>(bsum, boff);
  k_scanC<<<SCB,256,0,stream>>>(deg, boff, off, cur);
  k_scatter<<<3125,256,0,stream>>>(ei, cur, col);

  // ---- weight fragment pre-conversion (tiny, one-time) ----
  k_prepB<<<64,256,0,stream>>>(w_h, 128, 128, 1, BfH);
  k_prepBG<<<320,256,0,stream>>>(w_gat, BfG);
  k_prepB<<<256,256,0,stream>>>(w_out, 512, 128, 4, BfO);

  // ---- GCN1: agg in 3-dim, mm 3->128, BN, gelu ----
  k_agg3<<<196,256,0,stream>>>(x, off, col, dis, aggx3);
  k_mm_in<<<(NN*64+255)/256,256,0,stream>>>(aggx3, w_in, b_in, (u32*)F0);   // pre1=F0
  k_bn_part<<<dim3(1,PBN),256,0,stream>>>(F0, 128, 128, part);
  k_bn_fin<<<1,256,0,stream>>>(part, g_in, be_in, ssbuf, 128, 1.f/NN);
  k_bn_apply<false><<<2048,256,0,stream>>>((u32*)F0, ssbuf, nullptr, (u32*)F1); // h1=F1

  // ---- GCN2: agg(h1), mm 128->128 +b, BN, gelu, +res ----
  k_gcn_agg64<<<NN,64,0,stream>>>(F1, off, col, dis, F0);                   // aggH1=F0
  k_mm_mfma<<<dim3(782,1),256,0,stream>>>(F0, 128, NN, 128, BfH, F2, 128, b_h); // pre2=F2
  k_bn_part<<<dim3(1,PBN),256,0,stream>>>(F2, 128, 128, part);
  k_bn_fin<<<1,256,0,stream>>>(part, g_h, be_h, ssbuf, 128, 1.f/NN);
  k_bn_apply<true><<<2048,256,0,stream>>>((u32*)F2, ssbuf, (u32*)F1, (u32*)F0);  // h2=F0

  // ---- GAT: scores from h2, 1-pass prep (max-free), 1 gather, mm K=640 ----
  k_wv<<<5,128,0,stream>>>(w_gat, att_s, att_d, wvs, wvd);
  k_score10<<<NN,64,0,stream>>>(F0, wvs, wvd, asrc, adst);
  k_prep5<<<NN,64,0,stream>>>(asrc, adst, off, col, sv, aself5, invb5);
  k_gather5<<<NN,64,0,stream>>>(F0, off, col, sv, aself5, invb5, AGG5);
  k_mm_mfma<<<dim3(782,1),256,0,stream>>>(AGG5, 640, NN, 640, BfG, F1, 128, b_gat); // h3=F1

  // ---- GCN3: agg(h3), mm 128->512 +b (one dispatch, 4 col chunks) ----
  k_gcn_agg64<<<NN,64,0,stream>>>(F1, off, col, dis, F2);                   // aggH3=F2
  k_mm_mfma<<<dim3(782,4),256,0,stream>>>(F2, 128, NN, 128, BfO, A512, 512, b_out); // pre4=A512
  k_bn_part<<<dim3(4,PBN),256,0,stream>>>(A512, 512, 512, part);
  k_bn_fin<<<2,256,0,stream>>>(part, g_out, be_out, ssbuf, 512, 1.f/NN);

  // ---- fused graph-LN stats + mean pool (single pass; h4 never materialized) ----
  k_gstart<<<1,128,0,stream>>>(batch, gst);
  k_poolstat<<<dim3(NG,SPL),512,0,stream>>>(A512, ssbuf, gst, poolpart, sqpart);
  k_poolred<<<1,1024,0,stream>>>(poolpart, sqpart, scal);
  k_poolapply<<<NG,512,0,stream>>>(poolpart, gst, scal, g_ln, be_ln, pooled);

  // ---- projection head + classifier ----
  k_head_mm1<<<NG,128,0,stream>>>(pooled, w_p1, b_p1, q);
  k_head_bn<<<1,128,0,stream>>>(q, g_pbn, be_pbn, q2);
  k_head2c<<<NG,128,0,stream>>>(q2, w_p2, b_p2, g_pln, be_pln, w_c, b_c, out);
}

// Round 9
// 708.995 us; speedup vs baseline: 1.6843x; 1.6843x over previous
//
#include <hip/hip_runtime.h>
#include <hip/hip_bf16.h>
#include <math.h>

#define NN 50000
#define NE 800000
#define NG 64
#define NC 100
#define EPSV 1e-5f
#define PBN 256   // BN partial-sum slots (deterministic, no atomics)
#define SCB 196   // scan blocks (196*256 >= NN)
#define SPL 8     // pool splits per graph

typedef unsigned int   u32;
typedef unsigned short u16;
typedef __attribute__((ext_vector_type(8))) short bf16x8;
typedef __attribute__((ext_vector_type(4))) float f32x4;

__device__ __forceinline__ float gelu_f(float x){
  return 0.5f*x*(1.0f + erff(x*0.70710678118654752f));
}
__device__ __forceinline__ float bf2f(u16 u){
  return __uint_as_float(((u32)u)<<16);
}
__device__ __forceinline__ float2 bf2f2(u32 u){
  float2 r;
  r.x = __uint_as_float(u<<16);
  r.y = __uint_as_float(u & 0xffff0000u);
  return r;
}
__device__ __forceinline__ u16 f2bf(float f){
  __hip_bfloat16 h = __float2bfloat16(f);
  return *(u16*)&h;
}
__device__ __forceinline__ u32 pack_bf2(float a, float b){
  return (u32)f2bf(a) | ((u32)f2bf(b)<<16);
}

// ---------------- CSR construction ----------------
__global__ void k_deg_init(int* deg){
  int i = blockIdx.x*256 + threadIdx.x;
  if (i < NN) deg[i] = 1;           // self loop
}
__global__ void k_deg_hist(const int* ei, int* deg){
  int e = blockIdx.x*256 + threadIdx.x;
  if (e < NE) atomicAdd(&deg[ei[NE + e]], 1);   // dst row
}
__global__ void k_dis(const int* deg, float* dis){
  int i = blockIdx.x*256 + threadIdx.x;
  if (i < NN) dis[i] = rsqrtf((float)deg[i]);
}
// parallel exclusive scan of (deg-1)
__global__ void k_scanA(const int* deg, int* bsum){
  __shared__ int red[256];
  int b = blockIdx.x, t = threadIdx.x;
  int i = b*256 + t;
  red[t] = (i < NN) ? deg[i]-1 : 0;
  __syncthreads();
  for (int st = 128; st; st >>= 1){
    if (t < st) red[t] += red[t+st];
    __syncthreads();
  }
  if (t == 0) bsum[b] = red[0];
}
__global__ void k_scanB(const int* bsum, int* boff){
  __shared__ int sh[256];
  int t = threadIdx.x;
  sh[t] = (t < SCB) ? bsum[t] : 0;
  __syncthreads();
  for (int d = 1; d < 256; d <<= 1){
    int v = (t >= d) ? sh[t-d] : 0;
    __syncthreads();
    sh[t] += v;
    __syncthreads();
  }
  if (t == 0) boff[0] = 0;
  if (t < SCB) boff[t+1] = sh[t];
}
__global__ void k_scanC(const int* deg, const int* boff, int* off, int* cur){
  __shared__ int sh[256];
  int b = blockIdx.x, t = threadIdx.x;
  int i = b*256 + t;
  int v = (i < NN) ? deg[i]-1 : 0;
  sh[t] = v;
  __syncthreads();
  for (int d = 1; d < 256; d <<= 1){
    int u = (t >= d) ? sh[t-d] : 0;
    __syncthreads();
    sh[t] += u;
    __syncthreads();
  }
  if (i < NN){
    int excl = boff[b] + sh[t] - v;
    off[i] = excl; cur[i] = excl;
    if (i == NN-1) off[NN] = boff[b] + sh[t];
  }
}
__global__ void k_scatter(const int* ei, int* cur, int* col){
  int e = blockIdx.x*256 + threadIdx.x;
  if (e < NE){
    int s = ei[e], d = ei[NE + e];
    int p = atomicAdd(&cur[d], 1);
    col[p] = s;
  }
}

// ---------------- GCN1: aggregate in 3-dim input space ----------------
__global__ void k_agg3(const float* x, const int* off, const int* col,
                       const float* dis, float* aggx){
  int i = blockIdx.x*256 + threadIdx.x;
  if (i >= NN) return;
  float di = dis[i];
  float w0 = di*di;
  float a0 = w0*x[i*3], a1 = w0*x[i*3+1], a2 = w0*x[i*3+2];
  int lo = off[i], hi = off[i+1];
  for (int e = lo; e < hi; ++e){
    int s = col[e];
    float w = dis[s]*di;
    a0 += w*x[s*3]; a1 += w*x[s*3+1]; a2 += w*x[s*3+2];
  }
  aggx[i*3] = a0; aggx[i*3+1] = a1; aggx[i*3+2] = a2;
}

// ---------------- input matmul (K=3) ----------------
__global__ void k_mm_in(const float* aggx, const float* w, const float* bias, u32* outp){
  int gid = blockIdx.x*256 + threadIdx.x;
  if (gid >= NN*64) return;
  int i = gid >> 6, j2 = (gid & 63)*2;
  float a = aggx[i*3]*w[j2]   + aggx[i*3+1]*w[128+j2]   + aggx[i*3+2]*w[256+j2]   + bias[j2];
  float b = aggx[i*3]*w[j2+1] + aggx[i*3+1]*w[128+j2+1] + aggx[i*3+2]*w[256+j2+1] + bias[j2+1];
  outp[gid] = pack_bf2(a, b);
}

// ---------------- B pre-conversion to bf16 fragment-major ----------------
__global__ void k_prepB(const float* B, int ldB, int K, int ncc, u16* Bf){
  int gid = blockIdx.x*256 + threadIdx.x;
  int tot = ncc*K*128;
  if (gid >= tot) return;
  int cc = gid / (K*128);
  int rem = gid - cc*(K*128);
  int k = rem >> 7, n = rem & 127;
  int c128 = k >> 7, kk = k & 127;
  int nt = n >> 4, i = n & 15;
  int ks = kk >> 5, jg = (kk >> 3) & 3, e = kk & 7;
  size_t addr = (size_t)cc*K*128 +
                ((((size_t)(c128*8 + nt)*4 + ks)*4 + jg)*16 + i)*8 + e;
  Bf[addr] = f2bf(B[(size_t)k*ldB + cc*128 + n]);
}
__global__ void k_prepBG(const float* w_gat, u16* Bf){
  int gid = blockIdx.x*256 + threadIdx.x;
  if (gid >= 640*128) return;
  int k = gid >> 7, n = gid & 127;
  int h = k >> 7, kk = k & 127;
  int nt = n >> 4, i = n & 15;
  int ks = kk >> 5, jg = (kk >> 3) & 3, e = kk & 7;
  size_t addr = ((((size_t)(h*8 + nt)*4 + ks)*4 + jg)*16 + i)*8 + e;
  Bf[addr] = f2bf(0.2f * w_gat[(size_t)kk*640 + h*128 + n]);
}

// ---------------- MFMA matmul (coalesced C store via LDS) ----------------
__global__ __launch_bounds__(256) void k_mm_mfma(const u16* A, int lda, int M, int K,
                        const u16* Bf, u16* C, int ldC, const float* bias){
  __shared__ u16 ct[64*132];
  int tid = threadIdx.x;
  int w = tid >> 6, l = tid & 63;
  int jg = l >> 4, ii = l & 15;
  int m0 = blockIdx.x*64 + w*16;
  int cc = blockIdx.y;
  int arow = m0 + ii; if (arow >= M) arow = M-1;
  const u16* Bfc = Bf + (size_t)cc*K*128;
  f32x4 acc[8] = {};
  for (int c128 = 0; c128 < (K >> 7); ++c128){
    const u16* Ar = A + (size_t)arow*lda + c128*128;
    bf16x8 af[4];
    #pragma unroll
    for (int ks = 0; ks < 4; ++ks)
      af[ks] = *(const bf16x8*)(Ar + ks*32 + jg*8);
    #pragma unroll
    for (int nt = 0; nt < 8; ++nt){
      f32x4 a4 = acc[nt];
      #pragma unroll
      for (int ks = 0; ks < 4; ++ks){
        bf16x8 bfr = *(const bf16x8*)(Bfc +
            ((((size_t)(c128*8 + nt)*4 + ks)*4 + jg)*16 + ii)*8);
        a4 = __builtin_amdgcn_mfma_f32_16x16x32_bf16(af[ks], bfr, a4, 0, 0, 0);
      }
      acc[nt] = a4;
    }
  }
  int cOut = cc*128;
  int lrow0 = w*16 + jg*4;
  #pragma unroll
  for (int nt = 0; nt < 8; ++nt){
    float bv = bias[cOut + nt*16 + ii];
    #pragma unroll
    for (int r = 0; r < 4; ++r)
      ct[(lrow0 + r)*132 + nt*16 + ii] = f2bf(acc[nt][r] + bv);
  }
  __syncthreads();
  int lr0 = tid >> 6;
  int lc = tid & 63;
  #pragma unroll
  for (int rr = 0; rr < 16; ++rr){
    int lrow = rr*4 + lr0;
    int grow = blockIdx.x*64 + lrow;
    if (grow < M)
      *(u32*)(C + (size_t)grow*ldC + cOut + lc*2) = *(const u32*)(ct + lrow*132 + lc*2);
  }
}

// ---------------- GCN aggregate in 128-dim ----------------
__global__ void k_gcn_agg64(const u16* xw, const int* off, const int* col,
                            const float* dis, u16* out){
  int i = blockIdx.x, t = threadIdx.x;   // 64 threads
  float di = dis[i];
  float2 sv = bf2f2(((const u32*)(xw + (size_t)i*128))[t]);
  float w0 = di*di;
  float ax = w0*sv.x, ay = w0*sv.y;
  int lo = off[i], hi = off[i+1];
  int e = lo;
  for (; e + 4 <= hi; e += 4){
    int s0 = col[e], s1 = col[e+1], s2 = col[e+2], s3 = col[e+3];
    float wA = dis[s0]*di, wB = dis[s1]*di, wC = dis[s2]*di, wD = dis[s3]*di;
    float2 r0 = bf2f2(((const u32*)(xw + (size_t)s0*128))[t]);
    float2 r1 = bf2f2(((const u32*)(xw + (size_t)s1*128))[t]);
    float2 r2 = bf2f2(((const u32*)(xw + (size_t)s2*128))[t]);
    float2 r3 = bf2f2(((const u32*)(xw + (size_t)s3*128))[t]);
    ax += wA*r0.x; ay += wA*r0.y;
    ax += wB*r1.x; ay += wB*r1.y;
    ax += wC*r2.x; ay += wC*r2.y;
    ax += wD*r3.x; ay += wD*r3.y;
  }
  for (; e < hi; ++e){
    int s = col[e];
    float w = dis[s]*di;
    float2 rv = bf2f2(((const u32*)(xw + (size_t)s*128))[t]);
    ax += w*rv.x; ay += w*rv.y;
  }
  ((u32*)(out + (size_t)i*128))[t] = pack_bf2(ax, ay);
}

// ---------------- BatchNorm (vectorized partials, feature-major slots) ----------
// grid (W/128, PBN), 256 threads = 32 ft(ushort4) x 8 row lanes.
// In-block LDS reduce over row lanes -> ONE slot per (feature, p):
// part layout: part[f*2*PBN + p] = sum, part[f*2*PBN + PBN + p] = sumsq
__global__ void k_bn_part(const u16* x, int stride, int W, float* part){
  __shared__ float shs[8][132];
  __shared__ float shq[8][132];
  int t = threadIdx.x;
  int ft = t & 31, rl = t >> 5;
  int f0 = ft*4;
  int fbase = blockIdx.x*128;
  int p = blockIdx.y;
  float s0=0.f,s1=0.f,s2=0.f,s3=0.f, q0=0.f,q1=0.f,q2=0.f,q3=0.f;
  for (int r = p + PBN*rl; r < NN; r += PBN*8){
    ushort4 u = *(const ushort4*)(x + (size_t)r*stride + fbase + f0);
    float v0 = bf2f(u.x), v1 = bf2f(u.y), v2 = bf2f(u.z), v3 = bf2f(u.w);
    s0 += v0; s1 += v1; s2 += v2; s3 += v3;
    q0 += v0*v0; q1 += v1*v1; q2 += v2*v2; q3 += v3*v3;
  }
  shs[rl][f0] = s0; shs[rl][f0+1] = s1; shs[rl][f0+2] = s2; shs[rl][f0+3] = s3;
  shq[rl][f0] = q0; shq[rl][f0+1] = q1; shq[rl][f0+2] = q2; shq[rl][f0+3] = q3;
  __syncthreads();
  if (t < 128){
    float s = 0.f, q = 0.f;
    #pragma unroll
    for (int r = 0; r < 8; ++r){ s += shs[r][t]; q += shq[r][t]; }
    size_t fb = (size_t)(fbase + t)*2*PBN;
    part[fb + p] = s;
    part[fb + PBN + p] = q;
  }
}
// one block per feature; 256 threads = 256 slots (coalesced), LDS tree reduce
__global__ void k_bn_fin(const float* part, const float* g, const float* be,
                         float* ss, int W, float invn){
  __shared__ float rs[256], rq[256];
  int f = blockIdx.x, t = threadIdx.x;
  size_t fb = (size_t)f*2*PBN;
  rs[t] = part[fb + t];
  rq[t] = part[fb + PBN + t];
  __syncthreads();
  for (int st = 128; st; st >>= 1){
    if (t < st){ rs[t] += rs[t+st]; rq[t] += rq[t+st]; }
    __syncthreads();
  }
  if (t == 0){
    float mean = rs[0]*invn;
    float var  = rq[0]*invn - mean*mean;
    float sc = g[f]*rsqrtf(var + EPSV);
    ss[f] = sc;
    ss[W+f] = be[f] - mean*sc;
  }
}
template<bool RES>
__global__ void k_bn_apply(const u32* x, const float* ss, const u32* res, u32* out){
  const int n = NN*64;
  for (int idx = blockIdx.x*256 + threadIdx.x; idx < n; idx += gridDim.x*256){
    int f2 = (idx & 63)*2;
    float2 v = bf2f2(x[idx]);
    v.x = gelu_f(v.x*ss[f2]   + ss[128+f2]);
    v.y = gelu_f(v.y*ss[f2+1] + ss[128+f2+1]);
    if (RES){ float2 r = bf2f2(res[idx]); v.x += r.x; v.y += r.y; }
    out[idx] = pack_bf2(v.x, v.y);
  }
}

// ---------------- GAT ----------------
__global__ void k_wv(const float* w_gat, const float* att_s, const float* att_d,
                     float* wvs, float* wvd){
  int h = blockIdx.x, c = threadIdx.x;   // 5 blocks x 128
  float ss = 0.f, sd = 0.f;
  const float* wr = w_gat + (size_t)c*640 + h*128;
  const float* as = att_s + h*128;
  const float* ad = att_d + h*128;
  for (int k = 0; k < 128; ++k){
    float wv = wr[k];
    ss += wv*as[k]; sd += wv*ad[k];
  }
  wvs[h*128+c] = ss; wvd[h*128+c] = sd;
}

__global__ void k_score10(const u16* h2, const float* wvs, const float* wvd,
                          float* asrc, float* adst){
  int i = blockIdx.x, t = threadIdx.x;   // 64
  float2 v = bf2f2(((const u32*)(h2 + (size_t)i*128))[t]);
  int f2 = 2*t;
  #pragma unroll
  for (int h = 0; h < 5; ++h){
    float vs = v.x*wvs[h*128+f2] + v.y*wvs[h*128+f2+1];
    float vd = v.x*wvd[h*128+f2] + v.y*wvd[h*128+f2+1];
    #pragma unroll
    for (int d = 32; d; d >>= 1){ vs += __shfl_xor(vs, d); vd += __shfl_xor(vd, d); }
    if (t == 0){ asrc[i*5+h] = vs; adst[i*5+h] = vd; }
  }
}

// single pass, max-free softmax prep; numerators bf16-packed [NE][8]
__global__ void k_prep5(const float* asrc, const float* adst,
                        const int* off, const int* col,
                        u16* sv, float* aself5, float* invb5){
  int i = blockIdx.x, t = threadIdx.x;   // 64
  int lo = off[i], hi = off[i+1];
  float ad[5], dn[5];
  #pragma unroll
  for (int h = 0; h < 5; ++h){ ad[h] = adst[i*5+h]; dn[h] = 0.f; }
  for (int e = lo + t; e < hi; e += 64){
    int s = col[e];
    u16 nb[5];
    #pragma unroll
    for (int h = 0; h < 5; ++h){
      float v = asrc[s*5+h] + ad[h];
      v = (v > 0.f) ? v : 0.2f*v;
      float ex = expf(v);
      u16 qq = f2bf(ex);
      nb[h] = qq;
      dn[h] += bf2f(qq);
    }
    uint4 pk;
    pk.x = (u32)nb[0] | ((u32)nb[1] << 16);
    pk.y = (u32)nb[2] | ((u32)nb[3] << 16);
    pk.z = (u32)nb[4];
    pk.w = 0;
    *(uint4*)(sv + (size_t)e*8) = pk;
  }
  #pragma unroll
  for (int h = 0; h < 5; ++h)
    #pragma unroll
    for (int d = 32; d; d >>= 1) dn[h] += __shfl_xor(dn[h], d);
  if (t == 0){
    #pragma unroll
    for (int h = 0; h < 5; ++h){
      float es = asrc[i*5+h] + ad[h];
      es = (es > 0.f) ? es : 0.2f*es;
      float esf = expf(es);
      aself5[i*5+h] = esf;
      invb5[i*5+h] = 1.f/fmaxf(dn[h] + esf, 1e-16f);
    }
  }
}

// one gather pass, 5 alpha-weighted accumulators; agg5 [NN,640] bf16
__global__ void k_gather5(const u16* h2, const int* off, const int* col,
                          const u16* sv, const float* aself5, const float* invb5,
                          u16* agg5){
  int i = blockIdx.x, t = threadIdx.x;   // 64
  float2 svv = bf2f2(((const u32*)(h2 + (size_t)i*128))[t]);
  float ax[5], ay[5];
  #pragma unroll
  for (int h = 0; h < 5; ++h){
    float a = aself5[i*5+h];
    ax[h] = a*svv.x; ay[h] = a*svv.y;
  }
  int lo = off[i], hi = off[i+1];
  int e = lo;
  for (; e + 2 <= hi; e += 2){
    int s0 = col[e], s1 = col[e+1];
    uint4 p0 = *(const uint4*)(sv + (size_t)e*8);
    uint4 p1 = *(const uint4*)(sv + (size_t)(e+1)*8);
    float2 r0 = bf2f2(((const u32*)(h2 + (size_t)s0*128))[t]);
    float2 r1 = bf2f2(((const u32*)(h2 + (size_t)s1*128))[t]);
    float a00 = bf2f((u16)(p0.x & 0xffff)), a01 = bf2f((u16)(p0.x >> 16));
    float a02 = bf2f((u16)(p0.y & 0xffff)), a03 = bf2f((u16)(p0.y >> 16));
    float a04 = bf2f((u16)(p0.z & 0xffff));
    float a10 = bf2f((u16)(p1.x & 0xffff)), a11 = bf2f((u16)(p1.x >> 16));
    float a12 = bf2f((u16)(p1.y & 0xffff)), a13 = bf2f((u16)(p1.y >> 16));
    float a14 = bf2f((u16)(p1.z & 0xffff));
    ax[0] += a00*r0.x + a10*r1.x; ay[0] += a00*r0.y + a10*r1.y;
    ax[1] += a01*r0.x + a11*r1.x; ay[1] += a01*r0.y + a11*r1.y;
    ax[2] += a02*r0.x + a12*r1.x; ay[2] += a02*r0.y + a12*r1.y;
    ax[3] += a03*r0.x + a13*r1.x; ay[3] += a03*r0.y + a13*r1.y;
    ax[4] += a04*r0.x + a14*r1.x; ay[4] += a04*r0.y + a14*r1.y;
  }
  for (; e < hi; ++e){
    int s = col[e];
    uint4 pk = *(const uint4*)(sv + (size_t)e*8);
    float2 rv = bf2f2(((const u32*)(h2 + (size_t)s*128))[t]);
    float a0 = bf2f((u16)(pk.x & 0xffff)), a1 = bf2f((u16)(pk.x >> 16));
    float a2 = bf2f((u16)(pk.y & 0xffff)), a3 = bf2f((u16)(pk.y >> 16));
    float a4 = bf2f((u16)(pk.z & 0xffff));
    ax[0] += a0*rv.x; ay[0] += a0*rv.y;
    ax[1] += a1*rv.x; ay[1] += a1*rv.y;
    ax[2] += a2*rv.x; ay[2] += a2*rv.y;
    ax[3] += a3*rv.x; ay[3] += a3*rv.y;
    ax[4] += a4*rv.x; ay[4] += a4*rv.y;
  }
  #pragma unroll
  for (int h = 0; h < 5; ++h){
    float iv = invb5[i*5+h];
    ((u32*)(agg5 + (size_t)i*640 + h*128))[t] = pack_bf2(ax[h]*iv, ay[h]*iv);
  }
}

// ---------------- fused graph-LN stats + mean pool (single pass over A512) -------
__global__ void k_gstart(const int* batch, int* gs){
  int g = threadIdx.x;
  if (g > NG) return;
  int lo = 0, hi = NN;
  while (lo < hi){ int mid = (lo+hi) >> 1; if (batch[mid] < g) lo = mid+1; else hi = mid; }
  gs[g] = lo;
}
// grid (NG, SPL) x 512 threads: 128 f-threads (ushort4) x 4 row lanes
__global__ void k_poolstat(const u16* a512, const float* ss, const int* gs,
                           float* poolpart, float* sqpart){
  __shared__ float4 red4[512];
  __shared__ float redq[512];
  int g = blockIdx.x, sp = blockIdx.y, t = threadIdx.x;
  int ft = t & 127, rl = t >> 7;
  int f0 = ft*4;
  int lo = gs[g], hi = gs[g+1];
  float sc0 = ss[f0],     sc1 = ss[f0+1],     sc2 = ss[f0+2],     sc3 = ss[f0+3];
  float sh0 = ss[512+f0], sh1 = ss[512+f0+1], sh2 = ss[512+f0+2], sh3 = ss[512+f0+3];
  float4 s4 = {0.f,0.f,0.f,0.f};
  float q = 0.f;
  for (int r = lo + sp*4 + rl; r < hi; r += SPL*4){
    ushort4 u = *(const ushort4*)(a512 + (size_t)r*512 + f0);
    float v0 = gelu_f(bf2f(u.x)*sc0 + sh0);
    float v1 = gelu_f(bf2f(u.y)*sc1 + sh1);
    float v2 = gelu_f(bf2f(u.z)*sc2 + sh2);
    float v3 = gelu_f(bf2f(u.w)*sc3 + sh3);
    s4.x += v0; s4.y += v1; s4.z += v2; s4.w += v3;
    q += v0*v0 + v1*v1 + v2*v2 + v3*v3;
  }
  red4[t] = s4; redq[t] = q;
  __syncthreads();
  for (int st = 256; st; st >>= 1){
    if (t < st) redq[t] += redq[t+st];
    __syncthreads();
  }
  if (t == 0) sqpart[g*SPL + sp] = redq[0];
  if (rl == 0){
    float4 a = red4[t], b = red4[t+128], c = red4[t+256], d = red4[t+384];
    float4 o;
    o.x = a.x+b.x+c.x+d.x; o.y = a.y+b.y+c.y+d.y;
    o.z = a.z+b.z+c.z+d.z; o.w = a.w+b.w+c.w+d.w;
    ((float4*)poolpart)[((size_t)(g*SPL + sp))*128 + ft] = o;
  }
}
__global__ void k_poolred(const float* poolpart, const float* sqpart, float* scal){
  __shared__ float rs_[1024], rq_[1024];
  int t = threadIdx.x;
  float s = 0.f, q = 0.f;
  const int tot = NG*SPL*512;
  for (int i = t; i < tot; i += 1024) s += poolpart[i];
  for (int i = t; i < NG*SPL; i += 1024) q += sqpart[i];
  rs_[t] = s; rq_[t] = q;
  __syncthreads();
  for (int st = 512; st; st >>= 1){
    if (t < st){ rs_[t] += rs_[t+st]; rq_[t] += rq_[t+st]; }
    __syncthreads();
  }
  if (t == 0){
    float invn = 1.f/((float)NN*512.f);
    float mu  = rs_[0]*invn;
    float var = rq_[0]*invn - mu*mu;
    scal[2] = mu;
    scal[3] = rsqrtf(var + EPSV);
  }
}
__global__ void k_poolapply(const float* poolpart, const int* gs, const float* scal,
                            const float* gam, const float* bet, float* pooled){
  int g = blockIdx.x, f = threadIdx.x;   // 512
  float s = 0.f;
  #pragma unroll
  for (int sp = 0; sp < SPL; ++sp)
    s += poolpart[((size_t)(g*SPL + sp))*512 + f];
  float cnt = (float)max(gs[g+1] - gs[g], 1);
  pooled[g*512 + f] = (s/cnt - scal[2])*scal[3]*gam[f] + bet[f];
}

// ---------------- projection head + classifier (fp32, tiny) ----------------
__global__ void k_head_mm1(const float* pooled, const float* w, const float* b, float* q){
  int g = blockIdx.x, j = threadIdx.x;   // 128
  float s = b[j];
  const float* pr = pooled + g*512;
  for (int k = 0; k < 512; ++k) s += pr[k]*w[k*128+j];
  q[g*128+j] = s;
}
__global__ void k_head_bn(const float* qin, const float* g_, const float* be_, float* qout){
  int f = threadIdx.x;   // 128, single block
  float s = 0.f, sq = 0.f;
  for (int r = 0; r < NG; ++r){ float v = qin[r*128+f]; s += v; sq += v*v; }
  float mu = s*(1.f/NG), var = sq*(1.f/NG) - mu*mu;
  float sc = g_[f]*rsqrtf(var + EPSV);
  float sh = be_[f] - mu*sc;
  for (int r = 0; r < NG; ++r) qout[r*128+f] = gelu_f(qin[r*128+f]*sc + sh);
}
// head2 (mm + res + LN + L2-normalize) fused with classifier (log-softmax)
__global__ void k_head2c(const float* q2, const float* w, const float* b,
                         const float* gam, const float* bet,
                         const float* wc, const float* bc, float* out){
  int g = blockIdx.x, j = threadIdx.x;   // 128
  __shared__ float row[128], red[128], shv[3];
  row[j] = q2[g*128+j];
  __syncthreads();
  float s = b[j] + row[j];
  for (int k = 0; k < 128; ++k) s += row[k]*w[k*128+j];
  red[j] = s; __syncthreads();
  for (int st = 64; st; st >>= 1){ if (j < st) red[j] += red[j+st]; __syncthreads(); }
  if (j == 0) shv[0] = red[0]*(1.f/128.f);
  __syncthreads();
  float d = s - shv[0];
  red[j] = d*d; __syncthreads();
  for (int st = 64; st; st >>= 1){ if (j < st) red[j] += red[j+st]; __syncthreads(); }
  if (j == 0) shv[1] = rsqrtf(red[0]*(1.f/128.f) + EPSV);
  __syncthreads();
  float v = d*shv[1]*gam[j] + bet[j];
  red[j] = v*v; __syncthreads();
  for (int st = 64; st; st >>= 1){ if (j < st) red[j] += red[j+st]; __syncthreads(); }
  if (j == 0) shv[2] = 1.f/fmaxf(sqrtf(red[0]), 1e-12f);
  __syncthreads();
  float o = v*shv[2];
  out[g*128+j] = o;
  __syncthreads();
  row[j] = o;        // x1 row for classifier
  __syncthreads();
  float cs = -1e30f;
  if (j < NC){
    cs = bc[j];
    for (int k = 0; k < 128; ++k) cs += row[k]*wc[k*NC+j];
  }
  red[j] = cs; __syncthreads();
  for (int st = 64; st; st >>= 1){ if (j < st) red[j] = fmaxf(red[j], red[j+st]); __syncthreads(); }
  if (j == 0) shv[0] = red[0];
  __syncthreads();
  float e = (j < NC) ? expf(cs - shv[0]) : 0.f;
  red[j] = e; __syncthreads();
  for (int st = 64; st; st >>= 1){ if (j < st) red[j] += red[j+st]; __syncthreads(); }
  if (j == 0) shv[1] = logf(red[0]);
  __syncthreads();
  if (j < NC) out[NG*128 + g*NC+j] = cs - shv[0] - shv[1];
}

extern "C" void kernel_launch(void* const* d_in, const int* in_sizes, int n_in,
                              void* d_out, int out_size, void* d_ws, size_t ws_size,
                              hipStream_t stream){
  const float* x      = (const float*)d_in[0];
  const int*   ei     = (const int*)d_in[1];
  const int*   batch  = (const int*)d_in[2];
  const float* w_in   = (const float*)d_in[3];
  const float* b_in   = (const float*)d_in[4];
  const float* g_in   = (const float*)d_in[5];
  const float* be_in  = (const float*)d_in[6];
  const float* w_h    = (const float*)d_in[7];
  const float* b_h    = (const float*)d_in[8];
  const float* g_h    = (const float*)d_in[9];
  const float* be_h   = (const float*)d_in[10];
  const float* w_gat  = (const float*)d_in[11];
  const float* att_s  = (const float*)d_in[12];
  const float* att_d  = (const float*)d_in[13];
  const float* b_gat  = (const float*)d_in[14];
  const float* w_out  = (const float*)d_in[15];
  const float* b_out  = (const float*)d_in[16];
  const float* g_out  = (const float*)d_in[17];
  const float* be_out = (const float*)d_in[18];
  const float* g_ln   = (const float*)d_in[19];
  const float* be_ln  = (const float*)d_in[20];
  const float* w_p1   = (const float*)d_in[21];
  const float* b_p1   = (const float*)d_in[22];
  const float* g_pbn  = (const float*)d_in[23];
  const float* be_pbn = (const float*)d_in[24];
  const float* w_p2   = (const float*)d_in[25];
  const float* b_p2   = (const float*)d_in[26];
  const float* g_pln  = (const float*)d_in[27];
  const float* be_pln = (const float*)d_in[28];
  const float* w_c    = (const float*)d_in[29];
  const float* b_c    = (const float*)d_in[30];
  float* out = (float*)d_out;

  char* ws = (char*)d_ws;
  size_t o = 0;
  auto carve = [&](size_t bytes) -> char* {
    char* p = ws + o;
    o += (bytes + 255) & ~(size_t)255;
    return p;
  };
  int*   deg    = (int*)  carve((size_t)NN*4);
  int*   off    = (int*)  carve((size_t)(NN+1)*4);
  int*   cur    = (int*)  carve((size_t)NN*4);
  int*   col    = (int*)  carve((size_t)NE*4);
  float* dis    = (float*)carve((size_t)NN*4);
  int*   bsum   = (int*)  carve((size_t)SCB*4);
  int*   boff   = (int*)  carve((size_t)(SCB+1)*4);
  float* aggx3  = (float*)carve((size_t)NN*3*4);
  u16*   F0     = (u16*)  carve((size_t)NN*128*2);   // 12.8 MB
  u16*   F1     = (u16*)  carve((size_t)NN*128*2);
  u16*   F2     = (u16*)  carve((size_t)NN*128*2);   // aliased as sv during GAT
  u16*   AGG5   = (u16*)  carve((size_t)NN*640*2);   // 64 MB; later aliased as A512
  float* asrc   = (float*)carve((size_t)NN*5*4);
  float* adst   = (float*)carve((size_t)NN*5*4);
  float* aself5 = (float*)carve((size_t)NN*5*4);
  float* invb5  = (float*)carve((size_t)NN*5*4);
  float* wvs    = (float*)carve(640*4);
  float* wvd    = (float*)carve(640*4);
  u16*   BfH    = (u16*)  carve((size_t)128*128*2);
  u16*   BfG    = (u16*)  carve((size_t)640*128*2);
  u16*   BfO    = (u16*)  carve((size_t)128*512*2);
  float* part   = (float*)carve((size_t)512*2*PBN*4);   // 1 MB, feature-major
  float* poolpart = (float*)carve((size_t)NG*SPL*512*4); // 1 MB
  float* sqpart = (float*)carve((size_t)NG*SPL*4);
  float* ssbuf  = (float*)carve(1024*4);
  float* scal   = (float*)carve(64);
  int*   gst    = (int*)  carve(65*4);
  float* pooled = (float*)carve((size_t)NG*512*4);
  float* q      = (float*)carve((size_t)NG*128*4);
  float* q2     = (float*)carve((size_t)NG*128*4);
  if (o > ws_size) return;   // ~117 MB total

  u16* A512 = AGG5;        // [NN,512] bf16 reuses AGG5 (dead by then)
  u16* sv   = F2;          // [NE][8] bf16 numerators

  // ---- CSR build ----
  k_deg_init<<<196,256,0,stream>>>(deg);
  k_deg_hist<<<3125,256,0,stream>>>(ei, deg);
  k_dis<<<196,256,0,stream>>>(deg, dis);
  k_scanA<<<SCB,256,0,stream>>>(deg, bsum);
  k_scanB<<<1,256,0,stream>>>(bsum, boff);
  k_scanC<<<SCB,256,0,stream>>>(deg, boff, off, cur);
  k_scatter<<<3125,256,0,stream>>>(ei, cur, col);

  // ---- weight fragment pre-conversion (tiny, one-time) ----
  k_prepB<<<64,256,0,stream>>>(w_h, 128, 128, 1, BfH);
  k_prepBG<<<320,256,0,stream>>>(w_gat, BfG);
  k_prepB<<<256,256,0,stream>>>(w_out, 512, 128, 4, BfO);

  // ---- GCN1: agg in 3-dim, mm 3->128, BN, gelu ----
  k_agg3<<<196,256,0,stream>>>(x, off, col, dis, aggx3);
  k_mm_in<<<(NN*64+255)/256,256,0,stream>>>(aggx3, w_in, b_in, (u32*)F0);   // pre1=F0
  k_bn_part<<<dim3(1,PBN),256,0,stream>>>(F0, 128, 128, part);
  k_bn_fin<<<128,256,0,stream>>>(part, g_in, be_in, ssbuf, 128, 1.f/NN);
  k_bn_apply<false><<<2048,256,0,stream>>>((u32*)F0, ssbuf, nullptr, (u32*)F1); // h1=F1

  // ---- GCN2: agg(h1), mm 128->128 +b, BN, gelu, +res ----
  k_gcn_agg64<<<NN,64,0,stream>>>(F1, off, col, dis, F0);                   // aggH1=F0
  k_mm_mfma<<<dim3(782,1),256,0,stream>>>(F0, 128, NN, 128, BfH, F2, 128, b_h); // pre2=F2
  k_bn_part<<<dim3(1,PBN),256,0,stream>>>(F2, 128, 128, part);
  k_bn_fin<<<128,256,0,stream>>>(part, g_h, be_h, ssbuf, 128, 1.f/NN);
  k_bn_apply<true><<<2048,256,0,stream>>>((u32*)F2, ssbuf, (u32*)F1, (u32*)F0);  // h2=F0

  // ---- GAT: scores from h2, 1-pass prep (max-free), 1 gather, mm K=640 ----
  k_wv<<<5,128,0,stream>>>(w_gat, att_s, att_d, wvs, wvd);
  k_score10<<<NN,64,0,stream>>>(F0, wvs, wvd, asrc, adst);
  k_prep5<<<NN,64,0,stream>>>(asrc, adst, off, col, sv, aself5, invb5);
  k_gather5<<<NN,64,0,stream>>>(F0, off, col, sv, aself5, invb5, AGG5);
  k_mm_mfma<<<dim3(782,1),256,0,stream>>>(AGG5, 640, NN, 640, BfG, F1, 128, b_gat); // h3=F1

  // ---- GCN3: agg(h3), mm 128->512 +b (one dispatch, 4 col chunks) ----
  k_gcn_agg64<<<NN,64,0,stream>>>(F1, off, col, dis, F2);                   // aggH3=F2
  k_mm_mfma<<<dim3(782,4),256,0,stream>>>(F2, 128, NN, 128, BfO, A512, 512, b_out); // pre4=A512
  k_bn_part<<<dim3(4,PBN),256,0,stream>>>(A512, 512, 512, part);
  k_bn_fin<<<512,256,0,stream>>>(part, g_out, be_out, ssbuf, 512, 1.f/NN);

  // ---- fused graph-LN stats + mean pool (single pass; h4 never materialized) ----
  k_gstart<<<1,128,0,stream>>>(batch, gst);
  k_poolstat<<<dim3(NG,SPL),512,0,stream>>>(A512, ssbuf, gst, poolpart, sqpart);
  k_poolred<<<1,1024,0,stream>>>(poolpart, sqpart, scal);
  k_poolapply<<<NG,512,0,stream>>>(poolpart, gst, scal, g_ln, be_ln, pooled);

  // ---- projection head + classifier ----
  k_head_mm1<<<NG,128,0,stream>>>(pooled, w_p1, b_p1, q);
  k_head_bn<<<1,128,0,stream>>>(q, g_pbn, be_pbn, q2);
  k_head2c<<<NG,128,0,stream>>>(q2, w_p2, b_p2, g_pln, be_pln, w_c, b_c, out);
}

// Round 10
// 650.768 us; speedup vs baseline: 1.8350x; 1.0895x over previous
//
#include <hip/hip_runtime.h>
#include <hip/hip_bf16.h>
#include <math.h>

#define NN 50000
#define NE 800000
#define NG 64
#define NC 100
#define EPSV 1e-5f
#define PBN 256   // BN partial-sum slots (deterministic, no atomics)
#define SCB 196   // scan blocks (196*256 >= NN)
#define SPL 8     // pool splits per graph
#define PRB 128   // poolred stage-A blocks

typedef unsigned int   u32;
typedef unsigned short u16;
typedef __attribute__((ext_vector_type(8))) short bf16x8;
typedef __attribute__((ext_vector_type(4))) float f32x4;

__device__ __forceinline__ float gelu_f(float x){
  return 0.5f*x*(1.0f + erff(x*0.70710678118654752f));
}
__device__ __forceinline__ float bf2f(u16 u){
  return __uint_as_float(((u32)u)<<16);
}
__device__ __forceinline__ float2 bf2f2(u32 u){
  float2 r;
  r.x = __uint_as_float(u<<16);
  r.y = __uint_as_float(u & 0xffff0000u);
  return r;
}
__device__ __forceinline__ u16 f2bf(float f){
  __hip_bfloat16 h = __float2bfloat16(f);
  return *(u16*)&h;
}
__device__ __forceinline__ u32 pack_bf2(float a, float b){
  return (u32)f2bf(a) | ((u32)f2bf(b)<<16);
}

// ---------------- CSR construction ----------------
__global__ void k_deg_init(int* deg){
  int i = blockIdx.x*256 + threadIdx.x;
  if (i < NN) deg[i] = 1;           // self loop
}
__global__ void k_deg_hist(const int* ei, int* deg){
  int e = blockIdx.x*256 + threadIdx.x;
  if (e < NE) atomicAdd(&deg[ei[NE + e]], 1);   // dst row
}
__global__ void k_dis(const int* deg, float* dis){
  int i = blockIdx.x*256 + threadIdx.x;
  if (i < NN) dis[i] = rsqrtf((float)deg[i]);
}
// parallel exclusive scan of (deg-1)
__global__ void k_scanA(const int* deg, int* bsum){
  __shared__ int red[256];
  int b = blockIdx.x, t = threadIdx.x;
  int i = b*256 + t;
  red[t] = (i < NN) ? deg[i]-1 : 0;
  __syncthreads();
  for (int st = 128; st; st >>= 1){
    if (t < st) red[t] += red[t+st];
    __syncthreads();
  }
  if (t == 0) bsum[b] = red[0];
}
__global__ void k_scanB(const int* bsum, int* boff){
  __shared__ int sh[256];
  int t = threadIdx.x;
  sh[t] = (t < SCB) ? bsum[t] : 0;
  __syncthreads();
  for (int d = 1; d < 256; d <<= 1){
    int v = (t >= d) ? sh[t-d] : 0;
    __syncthreads();
    sh[t] += v;
    __syncthreads();
  }
  if (t == 0) boff[0] = 0;
  if (t < SCB) boff[t+1] = sh[t];
}
__global__ void k_scanC(const int* deg, const int* boff, int* off, int* cur){
  __shared__ int sh[256];
  int b = blockIdx.x, t = threadIdx.x;
  int i = b*256 + t;
  int v = (i < NN) ? deg[i]-1 : 0;
  sh[t] = v;
  __syncthreads();
  for (int d = 1; d < 256; d <<= 1){
    int u = (t >= d) ? sh[t-d] : 0;
    __syncthreads();
    sh[t] += u;
    __syncthreads();
  }
  if (i < NN){
    int excl = boff[b] + sh[t] - v;
    off[i] = excl; cur[i] = excl;
    if (i == NN-1) off[NN] = boff[b] + sh[t];
  }
}
__global__ void k_scatter(const int* ei, int* cur, int* col){
  int e = blockIdx.x*256 + threadIdx.x;
  if (e < NE){
    int s = ei[e], d = ei[NE + e];
    int p = atomicAdd(&cur[d], 1);
    col[p] = s;
  }
}

// ---------------- GCN1: aggregate in 3-dim input space ----------------
__global__ void k_agg3(const float* x, const int* off, const int* col,
                       const float* dis, float* aggx){
  int i = blockIdx.x*256 + threadIdx.x;
  if (i >= NN) return;
  float di = dis[i];
  float w0 = di*di;
  float a0 = w0*x[i*3], a1 = w0*x[i*3+1], a2 = w0*x[i*3+2];
  int lo = off[i], hi = off[i+1];
  for (int e = lo; e < hi; ++e){
    int s = col[e];
    float w = dis[s]*di;
    a0 += w*x[s*3]; a1 += w*x[s*3+1]; a2 += w*x[s*3+2];
  }
  aggx[i*3] = a0; aggx[i*3+1] = a1; aggx[i*3+2] = a2;
}

// ---------------- input matmul (K=3) ----------------
__global__ void k_mm_in(const float* aggx, const float* w, const float* bias, u32* outp){
  int gid = blockIdx.x*256 + threadIdx.x;
  if (gid >= NN*64) return;
  int i = gid >> 6, j2 = (gid & 63)*2;
  float a = aggx[i*3]*w[j2]   + aggx[i*3+1]*w[128+j2]   + aggx[i*3+2]*w[256+j2]   + bias[j2];
  float b = aggx[i*3]*w[j2+1] + aggx[i*3+1]*w[128+j2+1] + aggx[i*3+2]*w[256+j2+1] + bias[j2+1];
  outp[gid] = pack_bf2(a, b);
}

// ---------------- B pre-conversion to bf16 fragment-major ----------------
__global__ void k_prepB(const float* B, int ldB, int K, int ncc, u16* Bf){
  int gid = blockIdx.x*256 + threadIdx.x;
  int tot = ncc*K*128;
  if (gid >= tot) return;
  int cc = gid / (K*128);
  int rem = gid - cc*(K*128);
  int k = rem >> 7, n = rem & 127;
  int c128 = k >> 7, kk = k & 127;
  int nt = n >> 4, i = n & 15;
  int ks = kk >> 5, jg = (kk >> 3) & 3, e = kk & 7;
  size_t addr = (size_t)cc*K*128 +
                ((((size_t)(c128*8 + nt)*4 + ks)*4 + jg)*16 + i)*8 + e;
  Bf[addr] = f2bf(B[(size_t)k*ldB + cc*128 + n]);
}
__global__ void k_prepBG(const float* w_gat, u16* Bf){
  int gid = blockIdx.x*256 + threadIdx.x;
  if (gid >= 640*128) return;
  int k = gid >> 7, n = gid & 127;
  int h = k >> 7, kk = k & 127;
  int nt = n >> 4, i = n & 15;
  int ks = kk >> 5, jg = (kk >> 3) & 3, e = kk & 7;
  size_t addr = ((((size_t)(h*8 + nt)*4 + ks)*4 + jg)*16 + i)*8 + e;
  Bf[addr] = f2bf(0.2f * w_gat[(size_t)kk*640 + h*128 + n]);
}

// ---------------- MFMA matmul (coalesced C store via LDS) ----------------
__global__ __launch_bounds__(256) void k_mm_mfma(const u16* A, int lda, int M, int K,
                        const u16* Bf, u16* C, int ldC, const float* bias){
  __shared__ u16 ct[64*132];
  int tid = threadIdx.x;
  int w = tid >> 6, l = tid & 63;
  int jg = l >> 4, ii = l & 15;
  int m0 = blockIdx.x*64 + w*16;
  int cc = blockIdx.y;
  int arow = m0 + ii; if (arow >= M) arow = M-1;
  const u16* Bfc = Bf + (size_t)cc*K*128;
  f32x4 acc[8] = {};
  for (int c128 = 0; c128 < (K >> 7); ++c128){
    const u16* Ar = A + (size_t)arow*lda + c128*128;
    bf16x8 af[4];
    #pragma unroll
    for (int ks = 0; ks < 4; ++ks)
      af[ks] = *(const bf16x8*)(Ar + ks*32 + jg*8);
    #pragma unroll
    for (int nt = 0; nt < 8; ++nt){
      f32x4 a4 = acc[nt];
      #pragma unroll
      for (int ks = 0; ks < 4; ++ks){
        bf16x8 bfr = *(const bf16x8*)(Bfc +
            ((((size_t)(c128*8 + nt)*4 + ks)*4 + jg)*16 + ii)*8);
        a4 = __builtin_amdgcn_mfma_f32_16x16x32_bf16(af[ks], bfr, a4, 0, 0, 0);
      }
      acc[nt] = a4;
    }
  }
  int cOut = cc*128;
  int lrow0 = w*16 + jg*4;
  #pragma unroll
  for (int nt = 0; nt < 8; ++nt){
    float bv = bias[cOut + nt*16 + ii];
    #pragma unroll
    for (int r = 0; r < 4; ++r)
      ct[(lrow0 + r)*132 + nt*16 + ii] = f2bf(acc[nt][r] + bv);
  }
  __syncthreads();
  int lr0 = tid >> 6;
  int lc = tid & 63;
  #pragma unroll
  for (int rr = 0; rr < 16; ++rr){
    int lrow = rr*4 + lr0;
    int grow = blockIdx.x*64 + lrow;
    if (grow < M)
      *(u32*)(C + (size_t)grow*ldC + cOut + lc*2) = *(const u32*)(ct + lrow*132 + lc*2);
  }
}

// ---------------- GCN aggregate in 128-dim ----------------
__global__ void k_gcn_agg64(const u16* xw, const int* off, const int* col,
                            const float* dis, u16* out){
  int i = blockIdx.x, t = threadIdx.x;   // 64 threads
  float di = dis[i];
  float2 sv = bf2f2(((const u32*)(xw + (size_t)i*128))[t]);
  float w0 = di*di;
  float ax = w0*sv.x, ay = w0*sv.y;
  int lo = off[i], hi = off[i+1];
  int e = lo;
  for (; e + 4 <= hi; e += 4){
    int s0 = col[e], s1 = col[e+1], s2 = col[e+2], s3 = col[e+3];
    float wA = dis[s0]*di, wB = dis[s1]*di, wC = dis[s2]*di, wD = dis[s3]*di;
    float2 r0 = bf2f2(((const u32*)(xw + (size_t)s0*128))[t]);
    float2 r1 = bf2f2(((const u32*)(xw + (size_t)s1*128))[t]);
    float2 r2 = bf2f2(((const u32*)(xw + (size_t)s2*128))[t]);
    float2 r3 = bf2f2(((const u32*)(xw + (size_t)s3*128))[t]);
    ax += wA*r0.x; ay += wA*r0.y;
    ax += wB*r1.x; ay += wB*r1.y;
    ax += wC*r2.x; ay += wC*r2.y;
    ax += wD*r3.x; ay += wD*r3.y;
  }
  for (; e < hi; ++e){
    int s = col[e];
    float w = dis[s]*di;
    float2 rv = bf2f2(((const u32*)(xw + (size_t)s*128))[t]);
    ax += w*rv.x; ay += w*rv.y;
  }
  ((u32*)(out + (size_t)i*128))[t] = pack_bf2(ax, ay);
}

// ---------------- BatchNorm (vectorized partials, feature-major slots) ----------
__global__ void k_bn_part(const u16* x, int stride, int W, float* part){
  __shared__ float shs[8][132];
  __shared__ float shq[8][132];
  int t = threadIdx.x;
  int ft = t & 31, rl = t >> 5;
  int f0 = ft*4;
  int fbase = blockIdx.x*128;
  int p = blockIdx.y;
  float s0=0.f,s1=0.f,s2=0.f,s3=0.f, q0=0.f,q1=0.f,q2=0.f,q3=0.f;
  for (int r = p + PBN*rl; r < NN; r += PBN*8){
    ushort4 u = *(const ushort4*)(x + (size_t)r*stride + fbase + f0);
    float v0 = bf2f(u.x), v1 = bf2f(u.y), v2 = bf2f(u.z), v3 = bf2f(u.w);
    s0 += v0; s1 += v1; s2 += v2; s3 += v3;
    q0 += v0*v0; q1 += v1*v1; q2 += v2*v2; q3 += v3*v3;
  }
  shs[rl][f0] = s0; shs[rl][f0+1] = s1; shs[rl][f0+2] = s2; shs[rl][f0+3] = s3;
  shq[rl][f0] = q0; shq[rl][f0+1] = q1; shq[rl][f0+2] = q2; shq[rl][f0+3] = q3;
  __syncthreads();
  if (t < 128){
    float s = 0.f, q = 0.f;
    #pragma unroll
    for (int r = 0; r < 8; ++r){ s += shs[r][t]; q += shq[r][t]; }
    size_t fb = (size_t)(fbase + t)*2*PBN;
    part[fb + p] = s;
    part[fb + PBN + p] = q;
  }
}
__global__ void k_bn_fin(const float* part, const float* g, const float* be,
                         float* ss, int W, float invn){
  __shared__ float rs[256], rq[256];
  int f = blockIdx.x, t = threadIdx.x;
  size_t fb = (size_t)f*2*PBN;
  rs[t] = part[fb + t];
  rq[t] = part[fb + PBN + t];
  __syncthreads();
  for (int st = 128; st; st >>= 1){
    if (t < st){ rs[t] += rs[t+st]; rq[t] += rq[t+st]; }
    __syncthreads();
  }
  if (t == 0){
    float mean = rs[0]*invn;
    float var  = rq[0]*invn - mean*mean;
    float sc = g[f]*rsqrtf(var + EPSV);
    ss[f] = sc;
    ss[W+f] = be[f] - mean*sc;
  }
}
template<bool RES>
__global__ void k_bn_apply(const u32* x, const float* ss, const u32* res, u32* out){
  const int n = NN*64;
  for (int idx = blockIdx.x*256 + threadIdx.x; idx < n; idx += gridDim.x*256){
    int f2 = (idx & 63)*2;
    float2 v = bf2f2(x[idx]);
    v.x = gelu_f(v.x*ss[f2]   + ss[128+f2]);
    v.y = gelu_f(v.y*ss[f2+1] + ss[128+f2+1]);
    if (RES){ float2 r = bf2f2(res[idx]); v.x += r.x; v.y += r.y; }
    out[idx] = pack_bf2(v.x, v.y);
  }
}

// ---------------- GAT ----------------
__global__ void k_wv(const float* w_gat, const float* att_s, const float* att_d,
                     float* wvs, float* wvd){
  int h = blockIdx.x, c = threadIdx.x;   // 5 blocks x 128
  float ss = 0.f, sd = 0.f;
  const float* wr = w_gat + (size_t)c*640 + h*128;
  const float* as = att_s + h*128;
  const float* ad = att_d + h*128;
  for (int k = 0; k < 128; ++k){
    float wv = wr[k];
    ss += wv*as[k]; sd += wv*ad[k];
  }
  wvs[h*128+c] = ss; wvd[h*128+c] = sd;
}

__global__ void k_score10(const u16* h2, const float* wvs, const float* wvd,
                          float* asrc, float* adst){
  int i = blockIdx.x, t = threadIdx.x;   // 64
  float2 v = bf2f2(((const u32*)(h2 + (size_t)i*128))[t]);
  int f2 = 2*t;
  #pragma unroll
  for (int h = 0; h < 5; ++h){
    float vs = v.x*wvs[h*128+f2] + v.y*wvs[h*128+f2+1];
    float vd = v.x*wvd[h*128+f2] + v.y*wvd[h*128+f2+1];
    #pragma unroll
    for (int d = 32; d; d >>= 1){ vs += __shfl_xor(vs, d); vd += __shfl_xor(vd, d); }
    if (t == 0){ asrc[i*5+h] = vs; adst[i*5+h] = vd; }
  }
}

// single pass, max-free softmax prep; numerators bf16-packed [NE][8]
__global__ void k_prep5(const float* asrc, const float* adst,
                        const int* off, const int* col,
                        u16* sv, float* aself5, float* invb5){
  int i = blockIdx.x, t = threadIdx.x;   // 64
  int lo = off[i], hi = off[i+1];
  float ad[5], dn[5];
  #pragma unroll
  for (int h = 0; h < 5; ++h){ ad[h] = adst[i*5+h]; dn[h] = 0.f; }
  for (int e = lo + t; e < hi; e += 64){
    int s = col[e];
    u16 nb[5];
    #pragma unroll
    for (int h = 0; h < 5; ++h){
      float v = asrc[s*5+h] + ad[h];
      v = (v > 0.f) ? v : 0.2f*v;
      float ex = expf(v);
      u16 qq = f2bf(ex);
      nb[h] = qq;
      dn[h] += bf2f(qq);
    }
    uint4 pk;
    pk.x = (u32)nb[0] | ((u32)nb[1] << 16);
    pk.y = (u32)nb[2] | ((u32)nb[3] << 16);
    pk.z = (u32)nb[4];
    pk.w = 0;
    *(uint4*)(sv + (size_t)e*8) = pk;
  }
  #pragma unroll
  for (int h = 0; h < 5; ++h)
    #pragma unroll
    for (int d = 32; d; d >>= 1) dn[h] += __shfl_xor(dn[h], d);
  if (t == 0){
    #pragma unroll
    for (int h = 0; h < 5; ++h){
      float es = asrc[i*5+h] + ad[h];
      es = (es > 0.f) ? es : 0.2f*es;
      float esf = expf(es);
      aself5[i*5+h] = esf;
      invb5[i*5+h] = 1.f/fmaxf(dn[h] + esf, 1e-16f);
    }
  }
}

// one gather pass, 5 alpha-weighted accumulators; agg5 [NN,640] bf16
__global__ void k_gather5(const u16* h2, const int* off, const int* col,
                          const u16* sv, const float* aself5, const float* invb5,
                          u16* agg5){
  int i = blockIdx.x, t = threadIdx.x;   // 64
  float2 svv = bf2f2(((const u32*)(h2 + (size_t)i*128))[t]);
  float ax[5], ay[5];
  #pragma unroll
  for (int h = 0; h < 5; ++h){
    float a = aself5[i*5+h];
    ax[h] = a*svv.x; ay[h] = a*svv.y;
  }
  int lo = off[i], hi = off[i+1];
  int e = lo;
  for (; e + 2 <= hi; e += 2){
    int s0 = col[e], s1 = col[e+1];
    uint4 p0 = *(const uint4*)(sv + (size_t)e*8);
    uint4 p1 = *(const uint4*)(sv + (size_t)(e+1)*8);
    float2 r0 = bf2f2(((const u32*)(h2 + (size_t)s0*128))[t]);
    float2 r1 = bf2f2(((const u32*)(h2 + (size_t)s1*128))[t]);
    float a00 = bf2f((u16)(p0.x & 0xffff)), a01 = bf2f((u16)(p0.x >> 16));
    float a02 = bf2f((u16)(p0.y & 0xffff)), a03 = bf2f((u16)(p0.y >> 16));
    float a04 = bf2f((u16)(p0.z & 0xffff));
    float a10 = bf2f((u16)(p1.x & 0xffff)), a11 = bf2f((u16)(p1.x >> 16));
    float a12 = bf2f((u16)(p1.y & 0xffff)), a13 = bf2f((u16)(p1.y >> 16));
    float a14 = bf2f((u16)(p1.z & 0xffff));
    ax[0] += a00*r0.x + a10*r1.x; ay[0] += a00*r0.y + a10*r1.y;
    ax[1] += a01*r0.x + a11*r1.x; ay[1] += a01*r0.y + a11*r1.y;
    ax[2] += a02*r0.x + a12*r1.x; ay[2] += a02*r0.y + a12*r1.y;
    ax[3] += a03*r0.x + a13*r1.x; ay[3] += a03*r0.y + a13*r1.y;
    ax[4] += a04*r0.x + a14*r1.x; ay[4] += a04*r0.y + a14*r1.y;
  }
  for (; e < hi; ++e){
    int s = col[e];
    uint4 pk = *(const uint4*)(sv + (size_t)e*8);
    float2 rv = bf2f2(((const u32*)(h2 + (size_t)s*128))[t]);
    float a0 = bf2f((u16)(pk.x & 0xffff)), a1 = bf2f((u16)(pk.x >> 16));
    float a2 = bf2f((u16)(pk.y & 0xffff)), a3 = bf2f((u16)(pk.y >> 16));
    float a4 = bf2f((u16)(pk.z & 0xffff));
    ax[0] += a0*rv.x; ay[0] += a0*rv.y;
    ax[1] += a1*rv.x; ay[1] += a1*rv.y;
    ax[2] += a2*rv.x; ay[2] += a2*rv.y;
    ax[3] += a3*rv.x; ay[3] += a3*rv.y;
    ax[4] += a4*rv.x; ay[4] += a4*rv.y;
  }
  #pragma unroll
  for (int h = 0; h < 5; ++h){
    float iv = invb5[i*5+h];
    ((u32*)(agg5 + (size_t)i*640 + h*128))[t] = pack_bf2(ax[h]*iv, ay[h]*iv);
  }
}

// ---------------- fused graph-LN stats + mean pool (single pass over A512) -------
__global__ void k_gstart(const int* batch, int* gs){
  int g = threadIdx.x;
  if (g > NG) return;
  int lo = 0, hi = NN;
  while (lo < hi){ int mid = (lo+hi) >> 1; if (batch[mid] < g) lo = mid+1; else hi = mid; }
  gs[g] = lo;
}
// grid (NG, SPL) x 512 threads: 128 f-threads (ushort4) x 4 row lanes
__global__ void k_poolstat(const u16* a512, const float* ss, const int* gs,
                           float* poolpart, float* sqpart){
  __shared__ float4 red4[512];
  __shared__ float redq[512];
  int g = blockIdx.x, sp = blockIdx.y, t = threadIdx.x;
  int ft = t & 127, rl = t >> 7;
  int f0 = ft*4;
  int lo = gs[g], hi = gs[g+1];
  float sc0 = ss[f0],     sc1 = ss[f0+1],     sc2 = ss[f0+2],     sc3 = ss[f0+3];
  float sh0 = ss[512+f0], sh1 = ss[512+f0+1], sh2 = ss[512+f0+2], sh3 = ss[512+f0+3];
  float4 s4 = {0.f,0.f,0.f,0.f};
  float q = 0.f;
  for (int r = lo + sp*4 + rl; r < hi; r += SPL*4){
    ushort4 u = *(const ushort4*)(a512 + (size_t)r*512 + f0);
    float v0 = gelu_f(bf2f(u.x)*sc0 + sh0);
    float v1 = gelu_f(bf2f(u.y)*sc1 + sh1);
    float v2 = gelu_f(bf2f(u.z)*sc2 + sh2);
    float v3 = gelu_f(bf2f(u.w)*sc3 + sh3);
    s4.x += v0; s4.y += v1; s4.z += v2; s4.w += v3;
    q += v0*v0 + v1*v1 + v2*v2 + v3*v3;
  }
  red4[t] = s4; redq[t] = q;
  __syncthreads();
  for (int st = 256; st; st >>= 1){
    if (t < st) redq[t] += redq[t+st];
    __syncthreads();
  }
  if (t == 0) sqpart[g*SPL + sp] = redq[0];
  if (rl == 0){
    float4 a = red4[t], b = red4[t+128], c = red4[t+256], d = red4[t+384];
    float4 o;
    o.x = a.x+b.x+c.x+d.x; o.y = a.y+b.y+c.y+d.y;
    o.z = a.z+b.z+c.z+d.z; o.w = a.w+b.w+c.w+d.w;
    ((float4*)poolpart)[((size_t)(g*SPL + sp))*128 + ft] = o;
  }
}
// stage A: PRB blocks x 256 threads, deterministic block partials
__global__ void k_poolredA(const float* poolpart, const float* sqpart,
                           float* ppred, float* sqred){
  __shared__ float rs_[256], rq_[256];
  int b = blockIdx.x, t = threadIdx.x;
  float s = 0.f, q = 0.f;
  const int tot = NG*SPL*512;
  for (int i = b*256 + t; i < tot; i += PRB*256) s += poolpart[i];
  for (int i = b*256 + t; i < NG*SPL; i += PRB*256) q += sqpart[i];
  rs_[t] = s; rq_[t] = q;
  __syncthreads();
  for (int st = 128; st; st >>= 1){
    if (t < st){ rs_[t] += rs_[t+st]; rq_[t] += rq_[t+st]; }
    __syncthreads();
  }
  if (t == 0){ ppred[b] = rs_[0]; sqred[b] = rq_[0]; }
}
__global__ void k_poolredB(const float* ppred, const float* sqred, float* scal){
  __shared__ float rs_[128], rq_[128];
  int t = threadIdx.x;   // 128 = PRB
  rs_[t] = ppred[t]; rq_[t] = sqred[t];
  __syncthreads();
  for (int st = 64; st; st >>= 1){
    if (t < st){ rs_[t] += rs_[t+st]; rq_[t] += rq_[t+st]; }
    __syncthreads();
  }
  if (t == 0){
    float invn = 1.f/((float)NN*512.f);
    float mu  = rs_[0]*invn;
    float var = rq_[0]*invn - mu*mu;
    scal[2] = mu;
    scal[3] = rsqrtf(var + EPSV);
  }
}
__global__ void k_poolapply(const float* poolpart, const int* gs, const float* scal,
                            const float* gam, const float* bet, float* pooled){
  int g = blockIdx.x, f = threadIdx.x;   // 512
  float s = 0.f;
  #pragma unroll
  for (int sp = 0; sp < SPL; ++sp)
    s += poolpart[((size_t)(g*SPL + sp))*512 + f];
  float cnt = (float)max(gs[g+1] - gs[g], 1);
  pooled[g*512 + f] = (s/cnt - scal[2])*scal[3]*gam[f] + bet[f];
}

// ---------------- projection head + classifier (fp32, tiny) ----------------
__global__ void k_head_mm1(const float* pooled, const float* w, const float* b, float* q){
  int g = blockIdx.x, j = threadIdx.x;   // 128
  float s = b[j];
  const float* pr = pooled + g*512;
  for (int k = 0; k < 512; ++k) s += pr[k]*w[k*128+j];
  q[g*128+j] = s;
}
__global__ void k_head_bn(const float* qin, const float* g_, const float* be_, float* qout){
  int f = threadIdx.x;   // 128, single block
  float s = 0.f, sq = 0.f;
  for (int r = 0; r < NG; ++r){ float v = qin[r*128+f]; s += v; sq += v*v; }
  float mu = s*(1.f/NG), var = sq*(1.f/NG) - mu*mu;
  float sc = g_[f]*rsqrtf(var + EPSV);
  float sh = be_[f] - mu*sc;
  for (int r = 0; r < NG; ++r) qout[r*128+f] = gelu_f(qin[r*128+f]*sc + sh);
}
// head2 (mm + res + LN + L2-normalize) fused with classifier (log-softmax)
__global__ void k_head2c(const float* q2, const float* w, const float* b,
                         const float* gam, const float* bet,
                         const float* wc, const float* bc, float* out){
  int g = blockIdx.x, j = threadIdx.x;   // 128
  __shared__ float row[128], red[128], shv[3];
  row[j] = q2[g*128+j];
  __syncthreads();
  float s = b[j] + row[j];
  for (int k = 0; k < 128; ++k) s += row[k]*w[k*128+j];
  red[j] = s; __syncthreads();
  for (int st = 64; st; st >>= 1){ if (j < st) red[j] += red[j+st]; __syncthreads(); }
  if (j == 0) shv[0] = red[0]*(1.f/128.f);
  __syncthreads();
  float d = s - shv[0];
  red[j] = d*d; __syncthreads();
  for (int st = 64; st; st >>= 1){ if (j < st) red[j] += red[j+st]; __syncthreads(); }
  if (j == 0) shv[1] = rsqrtf(red[0]*(1.f/128.f) + EPSV);
  __syncthreads();
  float v = d*shv[1]*gam[j] + bet[j];
  red[j] = v*v; __syncthreads();
  for (int st = 64; st; st >>= 1){ if (j < st) red[j] += red[j+st]; __syncthreads(); }
  if (j == 0) shv[2] = 1.f/fmaxf(sqrtf(red[0]), 1e-12f);
  __syncthreads();
  float o = v*shv[2];
  out[g*128+j] = o;
  __syncthreads();
  row[j] = o;        // x1 row for classifier
  __syncthreads();
  float cs = -1e30f;
  if (j < NC){
    cs = bc[j];
    for (int k = 0; k < 128; ++k) cs += row[k]*wc[k*NC+j];
  }
  red[j] = cs; __syncthreads();
  for (int st = 64; st; st >>= 1){ if (j < st) red[j] = fmaxf(red[j], red[j+st]); __syncthreads(); }
  if (j == 0) shv[0] = red[0];
  __syncthreads();
  float e = (j < NC) ? expf(cs - shv[0]) : 0.f;
  red[j] = e; __syncthreads();
  for (int st = 64; st; st >>= 1){ if (j < st) red[j] += red[j+st]; __syncthreads(); }
  if (j == 0) shv[1] = logf(red[0]);
  __syncthreads();
  if (j < NC) out[NG*128 + g*NC+j] = cs - shv[0] - shv[1];
}

extern "C" void kernel_launch(void* const* d_in, const int* in_sizes, int n_in,
                              void* d_out, int out_size, void* d_ws, size_t ws_size,
                              hipStream_t stream){
  const float* x      = (const float*)d_in[0];
  const int*   ei     = (const int*)d_in[1];
  const int*   batch  = (const int*)d_in[2];
  const float* w_in   = (const float*)d_in[3];
  const float* b_in   = (const float*)d_in[4];
  const float* g_in   = (const float*)d_in[5];
  const float* be_in  = (const float*)d_in[6];
  const float* w_h    = (const float*)d_in[7];
  const float* b_h    = (const float*)d_in[8];
  const float* g_h    = (const float*)d_in[9];
  const float* be_h   = (const float*)d_in[10];
  const float* w_gat  = (const float*)d_in[11];
  const float* att_s  = (const float*)d_in[12];
  const float* att_d  = (const float*)d_in[13];
  const float* b_gat  = (const float*)d_in[14];
  const float* w_out  = (const float*)d_in[15];
  const float* b_out  = (const float*)d_in[16];
  const float* g_out  = (const float*)d_in[17];
  const float* be_out = (const float*)d_in[18];
  const float* g_ln   = (const float*)d_in[19];
  const float* be_ln  = (const float*)d_in[20];
  const float* w_p1   = (const float*)d_in[21];
  const float* b_p1   = (const float*)d_in[22];
  const float* g_pbn  = (const float*)d_in[23];
  const float* be_pbn = (const float*)d_in[24];
  const float* w_p2   = (const float*)d_in[25];
  const float* b_p2   = (const float*)d_in[26];
  const float* g_pln  = (const float*)d_in[27];
  const float* be_pln = (const float*)d_in[28];
  const float* w_c    = (const float*)d_in[29];
  const float* b_c    = (const float*)d_in[30];
  float* out = (float*)d_out;

  char* ws = (char*)d_ws;
  size_t o = 0;
  auto carve = [&](size_t bytes) -> char* {
    char* p = ws + o;
    o += (bytes + 255) & ~(size_t)255;
    return p;
  };
  int*   deg    = (int*)  carve((size_t)NN*4);
  int*   off    = (int*)  carve((size_t)(NN+1)*4);
  int*   cur    = (int*)  carve((size_t)NN*4);
  int*   col    = (int*)  carve((size_t)NE*4);
  float* dis    = (float*)carve((size_t)NN*4);
  int*   bsum   = (int*)  carve((size_t)SCB*4);
  int*   boff   = (int*)  carve((size_t)(SCB+1)*4);
  float* aggx3  = (float*)carve((size_t)NN*3*4);
  u16*   F0     = (u16*)  carve((size_t)NN*128*2);   // 12.8 MB
  u16*   F1     = (u16*)  carve((size_t)NN*128*2);
  u16*   F2     = (u16*)  carve((size_t)NN*128*2);   // aliased as sv during GAT
  u16*   AGG5   = (u16*)  carve((size_t)NN*640*2);   // 64 MB; later aliased as A512
  float* asrc   = (float*)carve((size_t)NN*5*4);
  float* adst   = (float*)carve((size_t)NN*5*4);
  float* aself5 = (float*)carve((size_t)NN*5*4);
  float* invb5  = (float*)carve((size_t)NN*5*4);
  float* wvs    = (float*)carve(640*4);
  float* wvd    = (float*)carve(640*4);
  u16*   BfH    = (u16*)  carve((size_t)128*128*2);
  u16*   BfG    = (u16*)  carve((size_t)640*128*2);
  u16*   BfO    = (u16*)  carve((size_t)128*512*2);
  float* part   = (float*)carve((size_t)512*2*PBN*4);   // 1 MB, feature-major
  float* poolpart = (float*)carve((size_t)NG*SPL*512*4); // 1 MB
  float* sqpart = (float*)carve((size_t)NG*SPL*4);
  float* ppred  = (float*)carve((size_t)PRB*4);
  float* sqred  = (float*)carve((size_t)PRB*4);
  float* ssbuf  = (float*)carve(1024*4);
  float* scal   = (float*)carve(64);
  int*   gst    = (int*)  carve(65*4);
  float* pooled = (float*)carve((size_t)NG*512*4);
  float* q      = (float*)carve((size_t)NG*128*4);
  float* q2     = (float*)carve((size_t)NG*128*4);
  if (o > ws_size) return;   // ~117 MB total

  u16* A512 = AGG5;        // [NN,512] bf16 reuses AGG5 (dead by then)
  u16* sv   = F2;          // [NE][8] bf16 numerators

  // ---- CSR build ----
  k_deg_init<<<196,256,0,stream>>>(deg);
  k_deg_hist<<<3125,256,0,stream>>>(ei, deg);
  k_dis<<<196,256,0,stream>>>(deg, dis);
  k_scanA<<<SCB,256,0,stream>>>(deg, bsum);
  k_scanB<<<1,256,0,stream>>>(bsum, boff);
  k_scanC<<<SCB,256,0,stream>>>(deg, boff, off, cur);
  k_scatter<<<3125,256,0,stream>>>(ei, cur, col);

  // ---- weight fragment pre-conversion (tiny, one-time) ----
  k_prepB<<<64,256,0,stream>>>(w_h, 128, 128, 1, BfH);
  k_prepBG<<<320,256,0,stream>>>(w_gat, BfG);
  k_prepB<<<256,256,0,stream>>>(w_out, 512, 128, 4, BfO);

  // ---- GCN1: agg in 3-dim, mm 3->128, BN, gelu ----
  k_agg3<<<196,256,0,stream>>>(x, off, col, dis, aggx3);
  k_mm_in<<<(NN*64+255)/256,256,0,stream>>>(aggx3, w_in, b_in, (u32*)F0);   // pre1=F0
  k_bn_part<<<dim3(1,PBN),256,0,stream>>>(F0, 128, 128, part);
  k_bn_fin<<<128,256,0,stream>>>(part, g_in, be_in, ssbuf, 128, 1.f/NN);
  k_bn_apply<false><<<2048,256,0,stream>>>((u32*)F0, ssbuf, nullptr, (u32*)F1); // h1=F1

  // ---- GCN2: agg(h1), mm 128->128 +b, BN, gelu, +res ----
  k_gcn_agg64<<<NN,64,0,stream>>>(F1, off, col, dis, F0);                   // aggH1=F0
  k_mm_mfma<<<dim3(782,1),256,0,stream>>>(F0, 128, NN, 128, BfH, F2, 128, b_h); // pre2=F2
  k_bn_part<<<dim3(1,PBN),256,0,stream>>>(F2, 128, 128, part);
  k_bn_fin<<<128,256,0,stream>>>(part, g_h, be_h, ssbuf, 128, 1.f/NN);
  k_bn_apply<true><<<2048,256,0,stream>>>((u32*)F2, ssbuf, (u32*)F1, (u32*)F0);  // h2=F0

  // ---- GAT: scores from h2, 1-pass prep (max-free), 1 gather, mm K=640 ----
  k_wv<<<5,128,0,stream>>>(w_gat, att_s, att_d, wvs, wvd);
  k_score10<<<NN,64,0,stream>>>(F0, wvs, wvd, asrc, adst);
  k_prep5<<<NN,64,0,stream>>>(asrc, adst, off, col, sv, aself5, invb5);
  k_gather5<<<NN,64,0,stream>>>(F0, off, col, sv, aself5, invb5, AGG5);
  k_mm_mfma<<<dim3(782,1),256,0,stream>>>(AGG5, 640, NN, 640, BfG, F1, 128, b_gat); // h3=F1

  // ---- GCN3: agg(h3), mm 128->512 +b (one dispatch, 4 col chunks) ----
  k_gcn_agg64<<<NN,64,0,stream>>>(F1, off, col, dis, F2);                   // aggH3=F2
  k_mm_mfma<<<dim3(782,4),256,0,stream>>>(F2, 128, NN, 128, BfO, A512, 512, b_out); // pre4=A512
  k_bn_part<<<dim3(4,PBN),256,0,stream>>>(A512, 512, 512, part);
  k_bn_fin<<<512,256,0,stream>>>(part, g_out, be_out, ssbuf, 512, 1.f/NN);

  // ---- fused graph-LN stats + mean pool (single pass; h4 never materialized) ----
  k_gstart<<<1,128,0,stream>>>(batch, gst);
  k_poolstat<<<dim3(NG,SPL),512,0,stream>>>(A512, ssbuf, gst, poolpart, sqpart);
  k_poolredA<<<PRB,256,0,stream>>>(poolpart, sqpart, ppred, sqred);
  k_poolredB<<<1,128,0,stream>>>(ppred, sqred, scal);
  k_poolapply<<<NG,512,0,stream>>>(poolpart, gst, scal, g_ln, be_ln, pooled);

  // ---- projection head + classifier ----
  k_head_mm1<<<NG,128,0,stream>>>(pooled, w_p1, b_p1, q);
  k_head_bn<<<1,128,0,stream>>>(q, g_pbn, be_pbn, q2);
  k_head2c<<<NG,128,0,stream>>>(q2, w_p2, b_p2, g_pln, be_pln, w_c, b_c, out);
}